// Round 2
// baseline (914.266 us; speedup 1.0000x reference)
//
#include <hip/hip_runtime.h>
#include <hip/hip_bf16.h>

typedef unsigned short u16;
typedef unsigned int u32;
typedef __attribute__((ext_vector_type(4))) float f32x4;
typedef __attribute__((ext_vector_type(8))) short short8;

#define DEV __device__ __forceinline__

// ---------- constants ----------
constexpr int Bc = 4, Tc = 64, Nc = 128, Dc = 256, Fc = 512;
constexpr int R = Bc * Tc * Nc;   // 32768 rows

// ---------- ws layout (bytes) ----------
constexpr size_t OFF_ABIN = 0;           // f32 [128*128]          65536
constexpr size_t OFF_DINV = 65536;       // f32 [128]              1024
constexpr size_t OFF_COLS = 66560;       // f32 [128]              1024
constexpr size_t OFF_AHT  = 67584;       // bf16 [128*128]         32768
constexpr size_t OFF_W1   = 100352;      // bf16 [3][1024][256]    1572864
constexpr size_t OFF_B1   = 1673216;     // f32 [3][1024]          12288
constexpr size_t OFF_GW   = 1685504;     // bf16 [2][512][512]     1048576
constexpr size_t OFF_CVEC = 2734080;     // f32 [2][512]           4096
constexpr size_t OFF_W2   = 2738176;     // bf16 [3][256][512]     786432
constexpr size_t OFF_BW   = 3524608;     // bf16 [256][768]        393216
constexpr size_t OFF_BTOT = 3917824;     // f32 [256]              1024
constexpr size_t OFF_CWT  = 3918848;     // f32 [192][64]          49152
constexpr size_t OFF_XHAT = 4194304;     // bf16 [R][256]          16777216
constexpr size_t OFF_U    = 20971520;    // bf16 [R][512]          33554432
constexpr size_t OFF_V    = 54525952;    // bf16 [R][512]          33554432
constexpr size_t OFF_S3   = 88080384;    // bf16 [R][512] / f32 [R][256]
constexpr size_t OFF_Y    = 121634816;   // bf16 [R][768]          50331648
constexpr size_t WS_NEED  = 171966464;

// ---------- helpers ----------
DEV u16 f2b(float f) { __hip_bfloat16 h = __float2bfloat16(f); return *(u16*)&h; }
DEV float b2f(u16 u) { union { u32 i; float f; } v; v.i = ((u32)u) << 16; return v.f; }
DEV u32 pack2(float a, float b) { return (u32)f2b(a) | ((u32)f2b(b) << 16); }
DEV float wave_sum(float s) {
  #pragma unroll
  for (int o = 32; o; o >>= 1) s += __shfl_xor(s, o);
  return s;
}
DEV float gelu(float v) { return 0.5f * v * (1.0f + erff(v * 0.70710678118654752f)); }

// ---------- adjacency ----------
__global__ void k_adj1(const int* __restrict__ cir, float* __restrict__ aBin) {
  int r = blockIdx.x, c = threadIdx.x;
  aBin[r * 128 + c] = (cir[r * 128 + c] != 0 || r == c) ? 1.f : 0.f;
}
__global__ void k_adj2(const float* __restrict__ aBin, float* __restrict__ dinv) {
  int c = threadIdx.x; float s = 0.f;
  for (int r = 0; r < 128; r++) s += aBin[r * 128 + c];
  dinv[c] = rsqrtf(s);
}
__global__ void k_adj3(const float* __restrict__ aBin, const float* __restrict__ dinv,
                       u16* __restrict__ ahat) {
  int r = blockIdx.x, c = threadIdx.x;
  ahat[r * 128 + c] = f2b(aBin[r * 128 + c] * dinv[r] * dinv[c]);
}
__global__ void k_adj4(const float* __restrict__ aBin, const float* __restrict__ dinv,
                       float* __restrict__ colsum) {
  int c = threadIdx.x; float s = 0.f;
  for (int r = 0; r < 128; r++) s += aBin[r * 128 + c] * dinv[r];
  colsum[c] = s * dinv[c];
}

// ---------- weight prep ----------
// W1'[k][d] = w1[k][d]*ng[d]; b1'[k] = b1[k] + sum_d w1[k][d]*nb[d]
__global__ void k_prep_w1(const float* __restrict__ w1, const float* __restrict__ ng,
                          const float* __restrict__ nb, const float* __restrict__ b1,
                          u16* __restrict__ w1o, float* __restrict__ b1o) {
  int k = blockIdx.x, lane = threadIdx.x;
  float4 wv = *(const float4*)(w1 + k * 256 + lane * 4);
  float4 gv = *(const float4*)(ng + lane * 4);
  float4 bv = *(const float4*)(nb + lane * 4);
  uint2 o; o.x = pack2(wv.x * gv.x, wv.y * gv.y); o.y = pack2(wv.z * gv.z, wv.w * gv.w);
  *(uint2*)(w1o + k * 256 + lane * 4) = o;
  float acc = wv.x * bv.x + wv.y * bv.y + wv.z * bv.z + wv.w * bv.w;
  acc = wave_sum(acc);
  if (lane == 0) b1o[k] = b1[k] + acc;
}
// gw'[f][e] = gw[f][e]*sg[e]; cvec[f] = sum_e gw[f][e]*sb[e]
__global__ void k_prep_gw(const float* __restrict__ gw, const float* __restrict__ sg,
                          const float* __restrict__ sb, u16* __restrict__ gwo,
                          float* __restrict__ cvo) {
  int f = blockIdx.x, lane = threadIdx.x;
  float acc = 0.f; uint4 o;
  float4 w0 = *(const float4*)(gw + f * 512 + lane * 8);
  float4 w1 = *(const float4*)(gw + f * 512 + lane * 8 + 4);
  float4 g0 = *(const float4*)(sg + lane * 8);
  float4 g1 = *(const float4*)(sg + lane * 8 + 4);
  float4 b0 = *(const float4*)(sb + lane * 8);
  float4 b1 = *(const float4*)(sb + lane * 8 + 4);
  o.x = pack2(w0.x * g0.x, w0.y * g0.y); o.y = pack2(w0.z * g0.z, w0.w * g0.w);
  o.z = pack2(w1.x * g1.x, w1.y * g1.y); o.w = pack2(w1.z * g1.z, w1.w * g1.w);
  acc = w0.x * b0.x + w0.y * b0.y + w0.z * b0.z + w0.w * b0.w
      + w1.x * b1.x + w1.y * b1.y + w1.z * b1.z + w1.w * b1.w;
  *(uint4*)(gwo + f * 512 + lane * 8) = o;
  acc = wave_sum(acc);
  if (lane == 0) cvo[f] = acc;
}
__global__ void k_b16cvt(const float* __restrict__ src, u16* __restrict__ dst) {
  int idx = (blockIdx.x * 64 + threadIdx.x) * 8;
  float4 a = *(const float4*)(src + idx);
  float4 b = *(const float4*)(src + idx + 4);
  uint4 o; o.x = pack2(a.x, a.y); o.y = pack2(a.z, a.w);
  o.z = pack2(b.x, b.y); o.w = pack2(b.z, b.w);
  *(uint4*)(dst + idx) = o;
}
// BW[o][c] = wout[o][c]*g_p[i]; btot[o] = bout[o] + sum_c wout[o][c]*b_p[i]
__global__ void k_prep_wout(const float* __restrict__ wout, const float* __restrict__ bout,
                            const float* __restrict__ g1, const float* __restrict__ b1,
                            const float* __restrict__ g2, const float* __restrict__ b2,
                            const float* __restrict__ g3, const float* __restrict__ b3,
                            u16* __restrict__ bw, float* __restrict__ bt) {
  int o = blockIdx.x, lane = threadIdx.x;
  float acc = 0.f;
  #pragma unroll
  for (int j = 0; j < 12; j++) {
    int c = lane + j * 64;
    int p = c >> 8, i = c & 255;
    const float* gg = (p == 0) ? g1 : (p == 1) ? g2 : g3;
    const float* bb = (p == 0) ? b1 : (p == 1) ? b2 : b3;
    float w = wout[o * 768 + c];
    bw[o * 768 + c] = f2b(w * gg[i]);
    acc += w * bb[i];
  }
  acc = wave_sum(acc);
  if (lane == 0) bt[o] = bout[o] + acc;
}
// cwT[(ti*3+k)*64 + t] = cw[t][ti][k]
__global__ void k_prep_cw(const float* __restrict__ cw, float* __restrict__ cwT) {
  int t = blockIdx.x, q = threadIdx.x;   // q = ti*3+k, 0..191
  cwT[q * 64 + t] = cw[t * 192 + q];
}

// ---------- LN kernels ----------
__global__ __launch_bounds__(256) void k_ln1(const float* __restrict__ x, u16* __restrict__ xhat) {
  int row = blockIdx.x * 4 + (threadIdx.x >> 6);
  int lane = threadIdx.x & 63;
  float4 v = *(const float4*)(x + (size_t)row * 256 + lane * 4);
  float s = v.x + v.y + v.z + v.w;
  float s2 = v.x * v.x + v.y * v.y + v.z * v.z + v.w * v.w;
  s = wave_sum(s); s2 = wave_sum(s2);
  float m = s * (1.f / 256.f);
  float var = s2 * (1.f / 256.f) - m * m;
  float rs = rsqrtf(var + 1e-5f);
  uint2 o; o.x = pack2((v.x - m) * rs, (v.y - m) * rs); o.y = pack2((v.z - m) * rs, (v.w - m) * rs);
  *(uint2*)(xhat + (size_t)row * 256 + lane * 4) = o;
}

// MODE 0: plain normalize (scale folded downstream). MODE 1: *sg+sb (conv branch).
template <int MODE>
__global__ __launch_bounds__(256) void k_lnv(const u16* __restrict__ Vin, u16* __restrict__ Vout,
                                             const float* __restrict__ sg, const float* __restrict__ sb) {
  int row = blockIdx.x * 4 + (threadIdx.x >> 6);
  int lane = threadIdx.x & 63;
  uint4 raw = *(const uint4*)(Vin + (size_t)row * 512 + lane * 8);
  u16* rp = (u16*)&raw;
  float f[8], s = 0.f, s2 = 0.f;
  #pragma unroll
  for (int j = 0; j < 8; j++) { f[j] = b2f(rp[j]); s += f[j]; s2 += f[j] * f[j]; }
  s = wave_sum(s); s2 = wave_sum(s2);
  float m = s * (1.f / 512.f);
  float var = s2 * (1.f / 512.f) - m * m;
  float rs = rsqrtf(var + 1e-5f);
  float o[8];
  if (MODE == 1) {
    float4 g0 = *(const float4*)(sg + lane * 8);
    float4 g1 = *(const float4*)(sg + lane * 8 + 4);
    float4 b0 = *(const float4*)(sb + lane * 8);
    float4 b1 = *(const float4*)(sb + lane * 8 + 4);
    o[0] = (f[0] - m) * rs * g0.x + b0.x; o[1] = (f[1] - m) * rs * g0.y + b0.y;
    o[2] = (f[2] - m) * rs * g0.z + b0.z; o[3] = (f[3] - m) * rs * g0.w + b0.w;
    o[4] = (f[4] - m) * rs * g1.x + b1.x; o[5] = (f[5] - m) * rs * g1.y + b1.y;
    o[6] = (f[6] - m) * rs * g1.z + b1.z; o[7] = (f[7] - m) * rs * g1.w + b1.w;
  } else {
    #pragma unroll
    for (int j = 0; j < 8; j++) o[j] = (f[j] - m) * rs;
  }
  uint4 ov; ov.x = pack2(o[0], o[1]); ov.y = pack2(o[2], o[3]);
  ov.z = pack2(o[4], o[5]); ov.w = pack2(o[6], o[7]);
  *(uint4*)(Vout + (size_t)row * 512 + lane * 8) = ov;
}

// y fp32 [R,256] -> normalized bf16 into Ycat[:, colofs:colofs+256]
__global__ __launch_bounds__(256) void k_lny(const float* __restrict__ Y, u16* __restrict__ Ycat, int colofs) {
  int row = blockIdx.x * 4 + (threadIdx.x >> 6);
  int lane = threadIdx.x & 63;
  float4 v = *(const float4*)(Y + (size_t)row * 256 + lane * 4);
  float s = v.x + v.y + v.z + v.w;
  float s2 = v.x * v.x + v.y * v.y + v.z * v.z + v.w * v.w;
  s = wave_sum(s); s2 = wave_sum(s2);
  float m = s * (1.f / 256.f);
  float var = s2 * (1.f / 256.f) - m * m;
  float rs = rsqrtf(var + 1e-5f);
  uint2 o; o.x = pack2((v.x - m) * rs, (v.y - m) * rs); o.y = pack2((v.z - m) * rs, (v.w - m) * rs);
  *(uint2*)(Ycat + (size_t)row * 768 + colofs + lane * 4) = o;
}

// ---------- MFMA GEMM: C[M,ncols] = A[M,K] @ Bt[ncols,K]^T ----------
// EPI 0: gelu(acc+bias), split-store bf16: col<512 -> out0, else out1 (stride 512)
// EPI 1: store bf16 raw to out0 (stride 512)
// EPI 2: acc + bias[col] + xres[row*256+col] -> f32 out0 (stride 256)
template <int KDIM, int EPI>
__global__ __launch_bounds__(256) void k_gemm(const u16* __restrict__ A, const u16* __restrict__ Bt,
                                              const float* __restrict__ bias,
                                              const float* __restrict__ xres,
                                              void* __restrict__ out0, void* __restrict__ out1) {
  __shared__ __align__(16) u16 As[128 * 64];
  __shared__ __align__(16) u16 Bs[128 * 64];
  const int tid = threadIdx.x;
  const int lane = tid & 63, wid = tid >> 6;
  const int wr = wid >> 1, wc = wid & 1;
  const int rowA0 = blockIdx.x * 128;
  const int colB0 = blockIdx.y * 128;

  f32x4 zero = {0.f, 0.f, 0.f, 0.f};
  f32x4 acc[4][4];
  #pragma unroll
  for (int m = 0; m < 4; m++)
    #pragma unroll
    for (int n = 0; n < 4; n++) acc[m][n] = zero;

  for (int k0 = 0; k0 < KDIM; k0 += 64) {
    #pragma unroll
    for (int i = 0; i < 4; i++) {
      int qq = tid + i * 256;
      int row = qq >> 3, kc = qq & 7;
      int boff = (row * 128 + kc * 16) ^ ((row & 7) << 4);
      uint4 va = *(const uint4*)(A + (size_t)(rowA0 + row) * KDIM + k0 + kc * 8);
      *(uint4*)((char*)As + boff) = va;
      uint4 vb = *(const uint4*)(Bt + (size_t)(colB0 + row) * KDIM + k0 + kc * 8);
      *(uint4*)((char*)Bs + boff) = vb;
    }
    __syncthreads();
    #pragma unroll
    for (int kk = 0; kk < 2; kk++) {
      int kb = kk * 64 + (lane >> 4) * 16;   // byte offset of this lane's k-group
      short8 af[4], bfr[4];
      #pragma unroll
      for (int m = 0; m < 4; m++) {
        int row = wr * 64 + m * 16 + (lane & 15);
        af[m] = *(const short8*)((char*)As + ((row * 128 + kb) ^ ((row & 7) << 4)));
      }
      #pragma unroll
      for (int n = 0; n < 4; n++) {
        int col = wc * 64 + n * 16 + (lane & 15);
        bfr[n] = *(const short8*)((char*)Bs + ((col * 128 + kb) ^ ((col & 7) << 4)));
      }
      #pragma unroll
      for (int m = 0; m < 4; m++)
        #pragma unroll
        for (int n = 0; n < 4; n++)
          acc[m][n] = __builtin_amdgcn_mfma_f32_16x16x32_bf16(af[m], bfr[n], acc[m][n], 0, 0, 0);
    }
    __syncthreads();
  }

  #pragma unroll
  for (int m = 0; m < 4; m++) {
    #pragma unroll
    for (int n = 0; n < 4; n++) {
      int col = colB0 + wc * 64 + n * 16 + (lane & 15);
      #pragma unroll
      for (int r = 0; r < 4; r++) {
        int row = rowA0 + wr * 64 + m * 16 + (lane >> 4) * 4 + r;
        float v = acc[m][n][r];
        if (EPI == 0) {
          v = gelu(v + bias[col]);
          u16 hv = f2b(v);
          if (col < 512) ((u16*)out0)[(size_t)row * 512 + col] = hv;
          else           ((u16*)out1)[(size_t)row * 512 + col - 512] = hv;
        } else if (EPI == 1) {
          ((u16*)out0)[(size_t)row * 512 + col] = f2b(v);
        } else {
          v += bias[col] + xres[(size_t)row * 256 + col];
          ((float*)out0)[(size_t)row * 256 + col] = v;
        }
      }
    }
  }
}

// ---------- conv branch spatial op: ug = u * (conv(vn) + cb) ----------
__global__ __launch_bounds__(256) void k_conv(const u16* __restrict__ vn, const u16* __restrict__ U,
                                              const float* __restrict__ cwT, const float* __restrict__ cb,
                                              u16* __restrict__ ug) {
  __shared__ __align__(16) float vsm[64][132];   // cols 0..129 = f-1 .. f+128
  int bx = blockIdx.x;
  int fc = bx & 3, bn = bx >> 2;
  int b = bn >> 7, n = bn & 127;
  int tid = threadIdx.x;
  {
    int ti = tid >> 2, part = tid & 3;
    size_t base = ((size_t)((b * 64 + ti) * 128 + n)) * 512 + fc * 128 + part * 32;
    #pragma unroll
    for (int v = 0; v < 4; v++) {
      uint4 raw = *(const uint4*)(vn + base + v * 8);
      u16* rp = (u16*)&raw;
      int c0 = 1 + part * 32 + v * 8;
      #pragma unroll
      for (int j = 0; j < 8; j++) vsm[ti][c0 + j] = b2f(rp[j]);
    }
  }
  if (tid < 128) {
    int ti = tid >> 1, side = tid & 1;
    size_t rowbase = ((size_t)((b * 64 + ti) * 128 + n)) * 512;
    if (side == 0) {
      int f = fc * 128 - 1;
      vsm[ti][0] = (f < 0) ? 0.f : b2f(vn[rowbase + f]);
    } else {
      int f = fc * 128 + 128;
      vsm[ti][129] = (f >= 512) ? 0.f : b2f(vn[rowbase + f]);
    }
  }
  __syncthreads();
  int t = tid & 63, fg = tid >> 6;
  int fb = fg * 32;
  float acc[32];
  #pragma unroll
  for (int j = 0; j < 32; j++) acc[j] = 0.f;
  for (int ti = 0; ti < 64; ti++) {
    float w0 = cwT[(ti * 3 + 0) * 64 + t];
    float w1 = cwT[(ti * 3 + 1) * 64 + t];
    float w2 = cwT[(ti * 3 + 2) * 64 + t];
    float win[36];
    #pragma unroll
    for (int q = 0; q < 9; q++) {
      float4 vv = *(const float4*)&vsm[ti][fb + 4 * q];
      win[4 * q] = vv.x; win[4 * q + 1] = vv.y; win[4 * q + 2] = vv.z; win[4 * q + 3] = vv.w;
    }
    #pragma unroll
    for (int j = 0; j < 32; j++)
      acc[j] += w0 * win[j] + w1 * win[j + 1] + w2 * win[j + 2];
  }
  float cbt = cb[t];
  size_t rowo = ((size_t)((b * 64 + t) * 128 + n)) * 512 + fc * 128 + fb;
  #pragma unroll
  for (int q = 0; q < 4; q++) {
    uint4 ur = *(const uint4*)(U + rowo + q * 8);
    u16* up = (u16*)&ur;
    float g0[8];
    #pragma unroll
    for (int j = 0; j < 8; j++) g0[j] = b2f(up[j]) * (acc[q * 8 + j] + cbt);
    uint4 ov; ov.x = pack2(g0[0], g0[1]); ov.y = pack2(g0[2], g0[3]);
    ov.z = pack2(g0[4], g0[5]); ov.w = pack2(g0[6], g0[7]);
    *(uint4*)(ug + rowo + q * 8) = ov;
  }
}

// ---------- GCN aggregation: ug = u * (a_hat^T @ glin + colsum*cvec + gb) ----------
__global__ __launch_bounds__(256) void k_agg(const u16* __restrict__ glin, const u16* __restrict__ U,
                                             const u16* __restrict__ ahat, const float* __restrict__ colsum,
                                             const float* __restrict__ cvec, const float* __restrict__ gb,
                                             u16* __restrict__ ug) {
  __shared__ __align__(16) u16 gsm[128][136];
  int bx = blockIdx.x;
  int fc = bx & 3, bt = bx >> 2;
  int tid = threadIdx.x;
  {
    int rs = tid >> 1, half = tid & 1;
    size_t base = ((size_t)(bt * 128 + rs)) * 512 + fc * 128 + half * 64;
    #pragma unroll
    for (int v = 0; v < 8; v++)
      *(uint4*)&gsm[rs][half * 64 + v * 8] = *(const uint4*)(glin + base + v * 8);
  }
  __syncthreads();
  int c = tid & 127, fh = tid >> 7;
  float acc[64];
  #pragma unroll
  for (int j = 0; j < 64; j++) acc[j] = 0.f;
  for (int r = 0; r < 128; r++) {
    float w = b2f(ahat[r * 128 + c]);
    #pragma unroll
    for (int q = 0; q < 8; q++) {
      uint4 raw = *(const uint4*)&gsm[r][fh * 64 + q * 8];
      u16* rp = (u16*)&raw;
      #pragma unroll
      for (int j = 0; j < 8; j++) acc[q * 8 + j] += w * b2f(rp[j]);
    }
  }
  int f0 = fc * 128 + fh * 64;
  float cs = colsum[c];
  size_t rowo = ((size_t)(bt * 128 + c)) * 512 + f0;
  #pragma unroll
  for (int q = 0; q < 8; q++) {
    uint4 ur = *(const uint4*)(U + rowo + q * 8);
    u16* up = (u16*)&ur;
    float g0[8];
    #pragma unroll
    for (int j = 0; j < 8; j++) {
      int f = f0 + q * 8 + j;
      g0[j] = b2f(up[j]) * (acc[q * 8 + j] + cs * cvec[f] + gb[f]);
    }
    uint4 ov; ov.x = pack2(g0[0], g0[1]); ov.y = pack2(g0[2], g0[3]);
    ov.z = pack2(g0[4], g0[5]); ov.w = pack2(g0[6], g0[7]);
    *(uint4*)(ug + rowo + q * 8) = ov;
  }
}

// ---------- launch ----------
extern "C" void kernel_launch(void* const* d_in, const int* in_sizes, int n_in,
                              void* d_out, int out_size, void* d_ws, size_t ws_size,
                              hipStream_t stream) {
  if (ws_size < WS_NEED) return;   // fails correctness visibly rather than corrupting
  const float* x = (const float*)d_in[0];
  const int* cir = (const int*)d_in[1];
  auto F32 = [&](int i) { return (const float*)d_in[i]; };

  char* W = (char*)d_ws;
  float* aBin   = (float*)(W + OFF_ABIN);
  float* dinv   = (float*)(W + OFF_DINV);
  float* colsum = (float*)(W + OFF_COLS);
  u16*   ahat   = (u16*)(W + OFF_AHT);
  u16*   W1c    = (u16*)(W + OFF_W1);
  float* b1c    = (float*)(W + OFF_B1);
  u16*   GWc    = (u16*)(W + OFF_GW);
  float* cvec   = (float*)(W + OFF_CVEC);
  u16*   W2c    = (u16*)(W + OFF_W2);
  u16*   BW     = (u16*)(W + OFF_BW);
  float* btot   = (float*)(W + OFF_BTOT);
  float* cwT    = (float*)(W + OFF_CWT);
  u16*   xhat   = (u16*)(W + OFF_XHAT);
  u16*   Ub     = (u16*)(W + OFF_U);
  u16*   Vb     = (u16*)(W + OFF_V);
  u16*   S3     = (u16*)(W + OFF_S3);
  u16*   Ycat   = (u16*)(W + OFF_Y);

  // prep
  k_adj1<<<128, 128, 0, stream>>>(cir, aBin);
  k_adj2<<<1, 128, 0, stream>>>(aBin, dinv);
  k_adj3<<<128, 128, 0, stream>>>(aBin, dinv, ahat);
  k_adj4<<<1, 128, 0, stream>>>(aBin, dinv, colsum);
  for (int p = 0; p < 3; p++) {
    int base = 2 + 8 * p;
    k_prep_w1<<<1024, 64, 0, stream>>>(F32(base + 2), F32(base + 0), F32(base + 1), F32(base + 3),
                                       W1c + (size_t)p * 1024 * 256, b1c + p * 1024);
    k_b16cvt<<<256, 64, 0, stream>>>(F32(base + 6), W2c + (size_t)p * 256 * 512);
  }
  k_prep_gw<<<512, 64, 0, stream>>>(F32(28), F32(14), F32(15), GWc, cvec);
  k_prep_gw<<<512, 64, 0, stream>>>(F32(30), F32(22), F32(23), GWc + 512 * 512, cvec + 512);
  k_prep_wout<<<256, 64, 0, stream>>>(F32(38), F32(39), F32(32), F32(33), F32(34), F32(35),
                                      F32(36), F32(37), BW, btot);
  k_prep_cw<<<64, 192, 0, stream>>>(F32(26), cwT);

  // shared LN(x)
  k_ln1<<<8192, 256, 0, stream>>>(x, xhat);

  // ---- branch t (conv) ----
  k_gemm<256, 0><<<dim3(256, 8), 256, 0, stream>>>(xhat, W1c, b1c, nullptr, Ub, Vb);
  k_lnv<1><<<8192, 256, 0, stream>>>(Vb, S3, F32(6), F32(7));
  k_conv<<<2048, 256, 0, stream>>>(S3, Ub, cwT, F32(27), Vb);
  k_gemm<512, 2><<<dim3(256, 2), 256, 0, stream>>>(Vb, W2c, F32(9), x, (void*)S3, nullptr);
  k_lny<<<8192, 256, 0, stream>>>((const float*)S3, Ycat, 0);

  // ---- branch s (GCN) ----
  k_gemm<256, 0><<<dim3(256, 8), 256, 0, stream>>>(xhat, W1c + (size_t)1 * 1024 * 256, b1c + 1024,
                                                   nullptr, Ub, Vb);
  k_lnv<0><<<8192, 256, 0, stream>>>(Vb, S3, nullptr, nullptr);
  k_gemm<512, 1><<<dim3(256, 4), 256, 0, stream>>>(S3, GWc, nullptr, nullptr, Vb, nullptr);
  k_agg<<<1024, 256, 0, stream>>>(Vb, Ub, ahat, colsum, cvec, F32(29), S3);
  k_gemm<512, 2><<<dim3(256, 2), 256, 0, stream>>>(S3, W2c + (size_t)1 * 256 * 512, F32(17), x,
                                                   (void*)Vb, nullptr);
  k_lny<<<8192, 256, 0, stream>>>((const float*)Vb, Ycat, 256);

  // ---- branch c (GCN) ----
  k_gemm<256, 0><<<dim3(256, 8), 256, 0, stream>>>(xhat, W1c + (size_t)2 * 1024 * 256, b1c + 2048,
                                                   nullptr, Ub, Vb);
  k_lnv<0><<<8192, 256, 0, stream>>>(Vb, S3, nullptr, nullptr);
  k_gemm<512, 1><<<dim3(256, 4), 256, 0, stream>>>(S3, GWc + 512 * 512, nullptr, nullptr, Vb, nullptr);
  k_agg<<<1024, 256, 0, stream>>>(Vb, Ub, ahat, colsum, cvec + 512, F32(31), S3);
  k_gemm<512, 2><<<dim3(256, 2), 256, 0, stream>>>(S3, W2c + (size_t)2 * 256 * 512, F32(25), x,
                                                   (void*)Vb, nullptr);
  k_lny<<<8192, 256, 0, stream>>>((const float*)Vb, Ycat, 512);

  // ---- final projection ----
  k_gemm<768, 2><<<dim3(256, 2), 256, 0, stream>>>(Ycat, BW, btot, x, d_out, nullptr);
}

// Round 3
// 622.692 us; speedup vs baseline: 1.4682x; 1.4682x over previous
//
#include <hip/hip_runtime.h>
#include <hip/hip_bf16.h>

typedef unsigned short u16;
typedef unsigned int u32;
typedef __attribute__((ext_vector_type(4))) float f32x4;
typedef __attribute__((ext_vector_type(8))) short short8;

#define DEV __device__ __forceinline__

// ---------- constants ----------
constexpr int Bc = 4, Tc = 64, Nc = 128, Dc = 256, Fc = 512;
constexpr int R = Bc * Tc * Nc;   // 32768 rows

// ---------- ws layout (bytes) ----------
constexpr size_t OFF_ABIN = 0;           // f32 [128*128]          65536
constexpr size_t OFF_DINV = 65536;       // f32 [128]              1024
constexpr size_t OFF_COLS = 66560;       // f32 [128]              1024
constexpr size_t OFF_AHT  = 67584;       // bf16 ahatT [c][r]      32768
constexpr size_t OFF_W1   = 100352;      // bf16 [3][1024][256]    1572864
constexpr size_t OFF_B1   = 1673216;     // f32 [3][1024]          12288
constexpr size_t OFF_GW   = 1685504;     // bf16 [2][512][512]     1048576
constexpr size_t OFF_CVEC = 2734080;     // f32 [2][512]           4096
constexpr size_t OFF_W2   = 2738176;     // bf16 [3][256][512]     786432
constexpr size_t OFF_BW   = 3524608;     // bf16 [256][768]        393216
constexpr size_t OFF_BTOT = 3917824;     // f32 [256]              1024
constexpr size_t OFF_CWT  = 3918848;     // bf16 cwA [64][192]     24576
constexpr size_t OFF_XHAT = 4194304;     // bf16 [R][256]          16777216
constexpr size_t OFF_U    = 20971520;    // bf16 [R][512]          33554432
constexpr size_t OFF_V    = 54525952;    // bf16 [R][512]          33554432
constexpr size_t OFF_S3   = 88080384;    // bf16 [R][512] / f32 [R][256]
constexpr size_t OFF_Y    = 121634816;   // bf16 [R][768]          50331648
constexpr size_t WS_NEED  = 171966464;

// ---------- helpers ----------
DEV u16 f2b(float f) { __hip_bfloat16 h = __float2bfloat16(f); return *(u16*)&h; }
DEV float b2f(u16 u) { union { u32 i; float f; } v; v.i = ((u32)u) << 16; return v.f; }
DEV u32 pack2(float a, float b) { return (u32)f2b(a) | ((u32)f2b(b) << 16); }
DEV float wave_sum(float s) {
  #pragma unroll
  for (int o = 32; o; o >>= 1) s += __shfl_xor(s, o);
  return s;
}
DEV float gelu(float v) { return 0.5f * v * (1.0f + erff(v * 0.70710678118654752f)); }

// ---------- adjacency ----------
__global__ void k_adj1(const int* __restrict__ cir, float* __restrict__ aBin) {
  int r = blockIdx.x, c = threadIdx.x;
  aBin[r * 128 + c] = (cir[r * 128 + c] != 0 || r == c) ? 1.f : 0.f;
}
__global__ void k_adj2(const float* __restrict__ aBin, float* __restrict__ dinv) {
  int c = threadIdx.x; float s = 0.f;
  for (int r = 0; r < 128; r++) s += aBin[r * 128 + c];
  dinv[c] = rsqrtf(s);
}
// ahatT[c][r] = a_hat[r][c]
__global__ void k_adj3(const float* __restrict__ aBin, const float* __restrict__ dinv,
                       u16* __restrict__ ahatT) {
  int c = blockIdx.x, r = threadIdx.x;
  ahatT[c * 128 + r] = f2b(aBin[r * 128 + c] * dinv[r] * dinv[c]);
}
__global__ void k_adj4(const float* __restrict__ aBin, const float* __restrict__ dinv,
                       float* __restrict__ colsum) {
  int c = threadIdx.x; float s = 0.f;
  for (int r = 0; r < 128; r++) s += aBin[r * 128 + c] * dinv[r];
  colsum[c] = s * dinv[c];
}

// ---------- weight prep ----------
__global__ void k_prep_w1(const float* __restrict__ w1, const float* __restrict__ ng,
                          const float* __restrict__ nb, const float* __restrict__ b1,
                          u16* __restrict__ w1o, float* __restrict__ b1o) {
  int k = blockIdx.x, lane = threadIdx.x;
  float4 wv = *(const float4*)(w1 + k * 256 + lane * 4);
  float4 gv = *(const float4*)(ng + lane * 4);
  float4 bv = *(const float4*)(nb + lane * 4);
  uint2 o; o.x = pack2(wv.x * gv.x, wv.y * gv.y); o.y = pack2(wv.z * gv.z, wv.w * gv.w);
  *(uint2*)(w1o + k * 256 + lane * 4) = o;
  float acc = wv.x * bv.x + wv.y * bv.y + wv.z * bv.z + wv.w * bv.w;
  acc = wave_sum(acc);
  if (lane == 0) b1o[k] = b1[k] + acc;
}
__global__ void k_prep_gw(const float* __restrict__ gw, const float* __restrict__ sg,
                          const float* __restrict__ sb, u16* __restrict__ gwo,
                          float* __restrict__ cvo) {
  int f = blockIdx.x, lane = threadIdx.x;
  float acc = 0.f; uint4 o;
  float4 w0 = *(const float4*)(gw + f * 512 + lane * 8);
  float4 w1 = *(const float4*)(gw + f * 512 + lane * 8 + 4);
  float4 g0 = *(const float4*)(sg + lane * 8);
  float4 g1 = *(const float4*)(sg + lane * 8 + 4);
  float4 b0 = *(const float4*)(sb + lane * 8);
  float4 b1 = *(const float4*)(sb + lane * 8 + 4);
  o.x = pack2(w0.x * g0.x, w0.y * g0.y); o.y = pack2(w0.z * g0.z, w0.w * g0.w);
  o.z = pack2(w1.x * g1.x, w1.y * g1.y); o.w = pack2(w1.z * g1.z, w1.w * g1.w);
  acc = w0.x * b0.x + w0.y * b0.y + w0.z * b0.z + w0.w * b0.w
      + w1.x * b1.x + w1.y * b1.y + w1.z * b1.z + w1.w * b1.w;
  *(uint4*)(gwo + f * 512 + lane * 8) = o;
  acc = wave_sum(acc);
  if (lane == 0) cvo[f] = acc;
}
__global__ void k_b16cvt(const float* __restrict__ src, u16* __restrict__ dst) {
  int idx = (blockIdx.x * 64 + threadIdx.x) * 8;
  float4 a = *(const float4*)(src + idx);
  float4 b = *(const float4*)(src + idx + 4);
  uint4 o; o.x = pack2(a.x, a.y); o.y = pack2(a.z, a.w);
  o.z = pack2(b.x, b.y); o.w = pack2(b.z, b.w);
  *(uint4*)(dst + idx) = o;
}
__global__ void k_prep_wout(const float* __restrict__ wout, const float* __restrict__ bout,
                            const float* __restrict__ g1, const float* __restrict__ b1,
                            const float* __restrict__ g2, const float* __restrict__ b2,
                            const float* __restrict__ g3, const float* __restrict__ b3,
                            u16* __restrict__ bw, float* __restrict__ bt) {
  int o = blockIdx.x, lane = threadIdx.x;
  float acc = 0.f;
  #pragma unroll
  for (int j = 0; j < 12; j++) {
    int c = lane + j * 64;
    int p = c >> 8, i = c & 255;
    const float* gg = (p == 0) ? g1 : (p == 1) ? g2 : g3;
    const float* bb = (p == 0) ? b1 : (p == 1) ? b2 : b3;
    float w = wout[o * 768 + c];
    bw[o * 768 + c] = f2b(w * gg[i]);
    acc += w * bb[i];
  }
  acc = wave_sum(acc);
  if (lane == 0) bt[o] = bout[o] + acc;
}
// cwA[t][K] with K = tap*64 + ti, from cw[t][ti][0][tap]
__global__ void k_prep_cwA(const float* __restrict__ cw, u16* __restrict__ cwA) {
  int t = blockIdx.x, q = threadIdx.x;   // q = 0..191
  int tap = q >> 6, ti = q & 63;
  cwA[t * 192 + q] = f2b(cw[t * 192 + ti * 3 + tap]);
}

// ---------- LN kernels ----------
__global__ __launch_bounds__(256) void k_ln1(const float* __restrict__ x, u16* __restrict__ xhat) {
  int row = blockIdx.x * 4 + (threadIdx.x >> 6);
  int lane = threadIdx.x & 63;
  float4 v = *(const float4*)(x + (size_t)row * 256 + lane * 4);
  float s = v.x + v.y + v.z + v.w;
  float s2 = v.x * v.x + v.y * v.y + v.z * v.z + v.w * v.w;
  s = wave_sum(s); s2 = wave_sum(s2);
  float m = s * (1.f / 256.f);
  float var = s2 * (1.f / 256.f) - m * m;
  float rs = rsqrtf(var + 1e-5f);
  uint2 o; o.x = pack2((v.x - m) * rs, (v.y - m) * rs); o.y = pack2((v.z - m) * rs, (v.w - m) * rs);
  *(uint2*)(xhat + (size_t)row * 256 + lane * 4) = o;
}

template <int MODE>
__global__ __launch_bounds__(256) void k_lnv(const u16* __restrict__ Vin, u16* __restrict__ Vout,
                                             const float* __restrict__ sg, const float* __restrict__ sb) {
  int row = blockIdx.x * 4 + (threadIdx.x >> 6);
  int lane = threadIdx.x & 63;
  uint4 raw = *(const uint4*)(Vin + (size_t)row * 512 + lane * 8);
  u16* rp = (u16*)&raw;
  float f[8], s = 0.f, s2 = 0.f;
  #pragma unroll
  for (int j = 0; j < 8; j++) { f[j] = b2f(rp[j]); s += f[j]; s2 += f[j] * f[j]; }
  s = wave_sum(s); s2 = wave_sum(s2);
  float m = s * (1.f / 512.f);
  float var = s2 * (1.f / 512.f) - m * m;
  float rs = rsqrtf(var + 1e-5f);
  float o[8];
  if (MODE == 1) {
    float4 g0 = *(const float4*)(sg + lane * 8);
    float4 g1 = *(const float4*)(sg + lane * 8 + 4);
    float4 b0 = *(const float4*)(sb + lane * 8);
    float4 b1 = *(const float4*)(sb + lane * 8 + 4);
    o[0] = (f[0] - m) * rs * g0.x + b0.x; o[1] = (f[1] - m) * rs * g0.y + b0.y;
    o[2] = (f[2] - m) * rs * g0.z + b0.z; o[3] = (f[3] - m) * rs * g0.w + b0.w;
    o[4] = (f[4] - m) * rs * g1.x + b1.x; o[5] = (f[5] - m) * rs * g1.y + b1.y;
    o[6] = (f[6] - m) * rs * g1.z + b1.z; o[7] = (f[7] - m) * rs * g1.w + b1.w;
  } else {
    #pragma unroll
    for (int j = 0; j < 8; j++) o[j] = (f[j] - m) * rs;
  }
  uint4 ov; ov.x = pack2(o[0], o[1]); ov.y = pack2(o[2], o[3]);
  ov.z = pack2(o[4], o[5]); ov.w = pack2(o[6], o[7]);
  *(uint4*)(Vout + (size_t)row * 512 + lane * 8) = ov;
}

__global__ __launch_bounds__(256) void k_lny(const float* __restrict__ Y, u16* __restrict__ Ycat, int colofs) {
  int row = blockIdx.x * 4 + (threadIdx.x >> 6);
  int lane = threadIdx.x & 63;
  float4 v = *(const float4*)(Y + (size_t)row * 256 + lane * 4);
  float s = v.x + v.y + v.z + v.w;
  float s2 = v.x * v.x + v.y * v.y + v.z * v.z + v.w * v.w;
  s = wave_sum(s); s2 = wave_sum(s2);
  float m = s * (1.f / 256.f);
  float var = s2 * (1.f / 256.f) - m * m;
  float rs = rsqrtf(var + 1e-5f);
  uint2 o; o.x = pack2((v.x - m) * rs, (v.y - m) * rs); o.y = pack2((v.z - m) * rs, (v.w - m) * rs);
  *(uint2*)(Ycat + (size_t)row * 768 + colofs + lane * 4) = o;
}

// ---------- MFMA GEMM: C[M,ncols] = A[M,K] @ Bt[ncols,K]^T ----------
// EPI 0: gelu(acc+bias), split-store bf16: col<512 -> out0, else out1 (stride 512)
// EPI 2: acc + bias[col] + xres[row*256+col] -> f32 out0 (stride 256)
template <int KDIM, int EPI>
__global__ __launch_bounds__(256) void k_gemm(const u16* __restrict__ A, const u16* __restrict__ Bt,
                                              const float* __restrict__ bias,
                                              const float* __restrict__ xres,
                                              void* __restrict__ out0, void* __restrict__ out1) {
  __shared__ __align__(16) u16 As[128 * 64];
  __shared__ __align__(16) u16 Bs[128 * 64];
  const int tid = threadIdx.x;
  const int lane = tid & 63, wid = tid >> 6;
  const int wr = wid >> 1, wc = wid & 1;
  const int rowA0 = blockIdx.x * 128;
  const int colB0 = blockIdx.y * 128;

  f32x4 zero = {0.f, 0.f, 0.f, 0.f};
  f32x4 acc[4][4];
  #pragma unroll
  for (int m = 0; m < 4; m++)
    #pragma unroll
    for (int n = 0; n < 4; n++) acc[m][n] = zero;

  for (int k0 = 0; k0 < KDIM; k0 += 64) {
    #pragma unroll
    for (int i = 0; i < 4; i++) {
      int qq = tid + i * 256;
      int row = qq >> 3, kc = qq & 7;
      int boff = (row * 128 + kc * 16) ^ ((row & 7) << 4);
      uint4 va = *(const uint4*)(A + (size_t)(rowA0 + row) * KDIM + k0 + kc * 8);
      *(uint4*)((char*)As + boff) = va;
      uint4 vb = *(const uint4*)(Bt + (size_t)(colB0 + row) * KDIM + k0 + kc * 8);
      *(uint4*)((char*)Bs + boff) = vb;
    }
    __syncthreads();
    #pragma unroll
    for (int kk = 0; kk < 2; kk++) {
      int kb = kk * 64 + (lane >> 4) * 16;
      short8 af[4], bfr[4];
      #pragma unroll
      for (int m = 0; m < 4; m++) {
        int row = wr * 64 + m * 16 + (lane & 15);
        af[m] = *(const short8*)((char*)As + ((row * 128 + kb) ^ ((row & 7) << 4)));
      }
      #pragma unroll
      for (int n = 0; n < 4; n++) {
        int col = wc * 64 + n * 16 + (lane & 15);
        bfr[n] = *(const short8*)((char*)Bs + ((col * 128 + kb) ^ ((col & 7) << 4)));
      }
      #pragma unroll
      for (int m = 0; m < 4; m++)
        #pragma unroll
        for (int n = 0; n < 4; n++)
          acc[m][n] = __builtin_amdgcn_mfma_f32_16x16x32_bf16(af[m], bfr[n], acc[m][n], 0, 0, 0);
    }
    __syncthreads();
  }

  #pragma unroll
  for (int m = 0; m < 4; m++) {
    #pragma unroll
    for (int n = 0; n < 4; n++) {
      int col = colB0 + wc * 64 + n * 16 + (lane & 15);
      #pragma unroll
      for (int r = 0; r < 4; r++) {
        int row = rowA0 + wr * 64 + m * 16 + (lane >> 4) * 4 + r;
        float v = acc[m][n][r];
        if (EPI == 0) {
          v = gelu(v + bias[col]);
          u16 hv = f2b(v);
          if (col < 512) ((u16*)out0)[(size_t)row * 512 + col] = hv;
          else           ((u16*)out1)[(size_t)row * 512 + col - 512] = hv;
        } else {
          v += bias[col] + xres[(size_t)row * 256 + col];
          ((float*)out0)[(size_t)row * 256 + col] = v;
        }
      }
    }
  }
}

// ---------- fused GCN: glin = A@GW^T (K=512), agg = ahatT@glin, ug = U*(agg + cs*cvec + gb) ----------
__global__ __launch_bounds__(256) void k_gcn(const u16* __restrict__ A, const u16* __restrict__ Bt,
                                             const u16* __restrict__ U, const u16* __restrict__ ahatT,
                                             const float* __restrict__ colsum, const float* __restrict__ cvec,
                                             const float* __restrict__ gb, u16* __restrict__ ug) {
  __shared__ __align__(16) char smem[34816];   // union: As+Bs (32768) / glinT 128x136 u16 (34816)
  u16* As = (u16*)smem;
  u16* Bs = (u16*)(smem + 16384);
  u16* glinT = (u16*)smem;
  const int tid = threadIdx.x;
  const int lane = tid & 63, wid = tid >> 6;
  const int wr = wid >> 1, wc = wid & 1;
  const int bt = blockIdx.x;
  const int rowA0 = bt * 128;
  const int colB0 = blockIdx.y * 128;

  f32x4 zero = {0.f, 0.f, 0.f, 0.f};
  f32x4 acc[4][4];
  #pragma unroll
  for (int m = 0; m < 4; m++)
    #pragma unroll
    for (int n = 0; n < 4; n++) acc[m][n] = zero;

  // ---- stage 1: glin tile [128 n][128 f] ----
  for (int k0 = 0; k0 < 512; k0 += 64) {
    #pragma unroll
    for (int i = 0; i < 4; i++) {
      int qq = tid + i * 256;
      int row = qq >> 3, kc = qq & 7;
      int boff = (row * 128 + kc * 16) ^ ((row & 7) << 4);
      uint4 va = *(const uint4*)(A + (size_t)(rowA0 + row) * 512 + k0 + kc * 8);
      *(uint4*)((char*)As + boff) = va;
      uint4 vb = *(const uint4*)(Bt + (size_t)(colB0 + row) * 512 + k0 + kc * 8);
      *(uint4*)((char*)Bs + boff) = vb;
    }
    __syncthreads();
    #pragma unroll
    for (int kk = 0; kk < 2; kk++) {
      int kb = kk * 64 + (lane >> 4) * 16;
      short8 af[4], bfr[4];
      #pragma unroll
      for (int m = 0; m < 4; m++) {
        int row = wr * 64 + m * 16 + (lane & 15);
        af[m] = *(const short8*)((char*)As + ((row * 128 + kb) ^ ((row & 7) << 4)));
      }
      #pragma unroll
      for (int n = 0; n < 4; n++) {
        int col = wc * 64 + n * 16 + (lane & 15);
        bfr[n] = *(const short8*)((char*)Bs + ((col * 128 + kb) ^ ((col & 7) << 4)));
      }
      #pragma unroll
      for (int m = 0; m < 4; m++)
        #pragma unroll
        for (int n = 0; n < 4; n++)
          acc[m][n] = __builtin_amdgcn_mfma_f32_16x16x32_bf16(af[m], bfr[n], acc[m][n], 0, 0, 0);
    }
    __syncthreads();
  }

  // ---- write glinT[f][n] (bf16, pad 136) ----
  #pragma unroll
  for (int m = 0; m < 4; m++) {
    #pragma unroll
    for (int n = 0; n < 4; n++) {
      int f = wc * 64 + n * 16 + (lane & 15);
      int n0 = wr * 64 + m * 16 + (lane >> 4) * 4;
      u32* p = (u32*)(glinT + f * 136 + n0);
      p[0] = pack2(acc[m][n][0], acc[m][n][1]);
      p[1] = pack2(acc[m][n][2], acc[m][n][3]);
    }
  }
  __syncthreads();

  // ---- stage 2: C2[c][f] = sum_r ahatT[c][r] * glin[r][f] ----
  f32x4 acc2[4][4];
  #pragma unroll
  for (int m = 0; m < 4; m++)
    #pragma unroll
    for (int n = 0; n < 4; n++) acc2[m][n] = zero;
  #pragma unroll
  for (int ks = 0; ks < 4; ks++) {
    short8 a2[4], b2v[4];
    #pragma unroll
    for (int m = 0; m < 4; m++) {
      int c = wr * 64 + m * 16 + (lane & 15);
      a2[m] = *(const short8*)(ahatT + c * 128 + ks * 32 + (lane >> 4) * 8);
    }
    #pragma unroll
    for (int n = 0; n < 4; n++) {
      int f = wc * 64 + n * 16 + (lane & 15);
      b2v[n] = *(const short8*)(glinT + f * 136 + ks * 32 + (lane >> 4) * 8);
    }
    #pragma unroll
    for (int m = 0; m < 4; m++)
      #pragma unroll
      for (int n = 0; n < 4; n++)
        acc2[m][n] = __builtin_amdgcn_mfma_f32_16x16x32_bf16(a2[m], b2v[n], acc2[m][n], 0, 0, 0);
  }

  // ---- epilogue: ug = U * (acc2 + colsum[c]*cvec[f] + gb[f]) ----
  #pragma unroll
  for (int m = 0; m < 4; m++) {
    #pragma unroll
    for (int n = 0; n < 4; n++) {
      int fl = wc * 64 + n * 16 + (lane & 15);
      int fg = colB0 + fl;
      float cv = cvec[fg], gbv = gb[fg];
      #pragma unroll
      for (int r = 0; r < 4; r++) {
        int c = wr * 64 + m * 16 + (lane >> 4) * 4 + r;
        size_t row = (size_t)(rowA0 + c) * 512 + fg;
        float g = b2f(U[row]) * (acc2[m][n][r] + colsum[c] * cv + gbv);
        ug[row] = f2b(g);
      }
    }
  }
}

// ---------- MFMA conv: out[t,f] = sum_tap sum_ti cwA[t][tap*64+ti]*vn[ti][f+tap-1]; ug = U*(out+cb) ----------
__global__ __launch_bounds__(256) void k_convm(const u16* __restrict__ vn, const u16* __restrict__ U,
                                               const u16* __restrict__ cwA, const float* __restrict__ cb,
                                               u16* __restrict__ ug) {
  __shared__ __align__(16) u16 vnT[258 * 72];   // [vrow = f_local + tap][ti], pad 72
  int bx = blockIdx.x;
  int n = bx & 127, b = (bx >> 7) & 3, h = bx >> 9;
  int tid = threadIdx.x;
  int lane = tid & 63, wid = tid >> 6;

  {
    int ti = tid & 63;
    size_t rowbase = ((size_t)((b * 64 + ti) * 128 + n)) * 512;
    #pragma unroll
    for (int it = 0; it < 8; it++) {
      int fq = (tid >> 6) + it * 4;   // 0..31
      uint4 raw = *(const uint4*)(vn + rowbase + h * 256 + fq * 8);
      u16* rp = (u16*)&raw;
      int vr = fq * 8 + 1;
      #pragma unroll
      for (int j = 0; j < 8; j++) vnT[(vr + j) * 72 + ti] = rp[j];
    }
    if (tid < 64) {
      vnT[0 * 72 + ti]   = (h == 0) ? (u16)0 : vn[rowbase + 255];
      vnT[257 * 72 + ti] = (h == 1) ? (u16)0 : vn[rowbase + 256];
    }
  }
  __syncthreads();

  f32x4 zero = {0.f, 0.f, 0.f, 0.f};
  f32x4 acc[4][4];
  #pragma unroll
  for (int m = 0; m < 4; m++)
    #pragma unroll
    for (int nn = 0; nn < 4; nn++) acc[m][nn] = zero;

  #pragma unroll
  for (int s = 0; s < 6; s++) {
    int tap = s >> 1;
    int K0 = s * 32;
    int tig = (s & 1) * 32 + (lane >> 4) * 8;
    short8 af[4], bf[4];
    #pragma unroll
    for (int m = 0; m < 4; m++) {
      int t = m * 16 + (lane & 15);
      af[m] = *(const short8*)(cwA + t * 192 + K0 + (lane >> 4) * 8);
    }
    #pragma unroll
    for (int nn = 0; nn < 4; nn++) {
      int fl = wid * 64 + nn * 16 + (lane & 15);
      int vr = fl + tap;
      bf[nn] = *(const short8*)(vnT + vr * 72 + tig);
    }
    #pragma unroll
    for (int m = 0; m < 4; m++)
      #pragma unroll
      for (int nn = 0; nn < 4; nn++)
        acc[m][nn] = __builtin_amdgcn_mfma_f32_16x16x32_bf16(af[m], bf[nn], acc[m][nn], 0, 0, 0);
  }

  #pragma unroll
  for (int m = 0; m < 4; m++) {
    #pragma unroll
    for (int nn = 0; nn < 4; nn++) {
      int fl = wid * 64 + nn * 16 + (lane & 15);
      int fg = h * 256 + fl;
      #pragma unroll
      for (int r = 0; r < 4; r++) {
        int t = m * 16 + (lane >> 4) * 4 + r;
        size_t row = ((size_t)((b * 64 + t) * 128 + n)) * 512 + fg;
        float g = b2f(U[row]) * (acc[m][nn][r] + cb[t]);
        ug[row] = f2b(g);
      }
    }
  }
}

// ---------- launch ----------
extern "C" void kernel_launch(void* const* d_in, const int* in_sizes, int n_in,
                              void* d_out, int out_size, void* d_ws, size_t ws_size,
                              hipStream_t stream) {
  if (ws_size < WS_NEED) return;
  const float* x = (const float*)d_in[0];
  const int* cir = (const int*)d_in[1];
  auto F32 = [&](int i) { return (const float*)d_in[i]; };

  char* W = (char*)d_ws;
  float* aBin   = (float*)(W + OFF_ABIN);
  float* dinv   = (float*)(W + OFF_DINV);
  float* colsum = (float*)(W + OFF_COLS);
  u16*   ahatT  = (u16*)(W + OFF_AHT);
  u16*   W1c    = (u16*)(W + OFF_W1);
  float* b1c    = (float*)(W + OFF_B1);
  u16*   GWc    = (u16*)(W + OFF_GW);
  float* cvec   = (float*)(W + OFF_CVEC);
  u16*   W2c    = (u16*)(W + OFF_W2);
  u16*   BW     = (u16*)(W + OFF_BW);
  float* btot   = (float*)(W + OFF_BTOT);
  u16*   cwA    = (u16*)(W + OFF_CWT);
  u16*   xhat   = (u16*)(W + OFF_XHAT);
  u16*   Ub     = (u16*)(W + OFF_U);
  u16*   Vb     = (u16*)(W + OFF_V);
  u16*   S3     = (u16*)(W + OFF_S3);
  u16*   Ycat   = (u16*)(W + OFF_Y);

  // prep
  k_adj1<<<128, 128, 0, stream>>>(cir, aBin);
  k_adj2<<<1, 128, 0, stream>>>(aBin, dinv);
  k_adj3<<<128, 128, 0, stream>>>(aBin, dinv, ahatT);
  k_adj4<<<1, 128, 0, stream>>>(aBin, dinv, colsum);
  for (int p = 0; p < 3; p++) {
    int base = 2 + 8 * p;
    k_prep_w1<<<1024, 64, 0, stream>>>(F32(base + 2), F32(base + 0), F32(base + 1), F32(base + 3),
                                       W1c + (size_t)p * 1024 * 256, b1c + p * 1024);
    k_b16cvt<<<256, 64, 0, stream>>>(F32(base + 6), W2c + (size_t)p * 256 * 512);
  }
  k_prep_gw<<<512, 64, 0, stream>>>(F32(28), F32(14), F32(15), GWc, cvec);
  k_prep_gw<<<512, 64, 0, stream>>>(F32(30), F32(22), F32(23), GWc + 512 * 512, cvec + 512);
  k_prep_wout<<<256, 64, 0, stream>>>(F32(38), F32(39), F32(32), F32(33), F32(34), F32(35),
                                      F32(36), F32(37), BW, btot);
  k_prep_cwA<<<64, 192, 0, stream>>>(F32(26), cwA);

  // shared LN(x)
  k_ln1<<<8192, 256, 0, stream>>>(x, xhat);

  // ---- branch t (conv) ----
  k_gemm<256, 0><<<dim3(256, 8), 256, 0, stream>>>(xhat, W1c, b1c, nullptr, Ub, Vb);
  k_lnv<1><<<8192, 256, 0, stream>>>(Vb, S3, F32(6), F32(7));
  k_convm<<<1024, 256, 0, stream>>>(S3, Ub, cwA, F32(27), Vb);
  k_gemm<512, 2><<<dim3(256, 2), 256, 0, stream>>>(Vb, W2c, F32(9), x, (void*)S3, nullptr);
  k_lny<<<8192, 256, 0, stream>>>((const float*)S3, Ycat, 0);

  // ---- branch s (GCN) ----
  k_gemm<256, 0><<<dim3(256, 8), 256, 0, stream>>>(xhat, W1c + (size_t)1 * 1024 * 256, b1c + 1024,
                                                   nullptr, Ub, Vb);
  k_lnv<0><<<8192, 256, 0, stream>>>(Vb, S3, nullptr, nullptr);
  k_gcn<<<dim3(256, 4), 256, 0, stream>>>(S3, GWc, Ub, ahatT, colsum, cvec, F32(29), Vb);
  k_gemm<512, 2><<<dim3(256, 2), 256, 0, stream>>>(Vb, W2c + (size_t)1 * 256 * 512, F32(17), x,
                                                   (void*)S3, nullptr);
  k_lny<<<8192, 256, 0, stream>>>((const float*)S3, Ycat, 256);

  // ---- branch c (GCN) ----
  k_gemm<256, 0><<<dim3(256, 8), 256, 0, stream>>>(xhat, W1c + (size_t)2 * 1024 * 256, b1c + 2048,
                                                   nullptr, Ub, Vb);
  k_lnv<0><<<8192, 256, 0, stream>>>(Vb, S3, nullptr, nullptr);
  k_gcn<<<dim3(256, 4), 256, 0, stream>>>(S3, GWc + 512 * 512, Ub, ahatT, colsum, cvec + 512, F32(31), Vb);
  k_gemm<512, 2><<<dim3(256, 2), 256, 0, stream>>>(Vb, W2c + (size_t)2 * 256 * 512, F32(25), x,
                                                   (void*)S3, nullptr);
  k_lny<<<8192, 256, 0, stream>>>((const float*)S3, Ycat, 512);

  // ---- final projection ----
  k_gemm<768, 2><<<dim3(256, 2), 256, 0, stream>>>(Ycat, BW, btot, x, d_out, nullptr);
}

// Round 4
// 608.059 us; speedup vs baseline: 1.5036x; 1.0241x over previous
//
#include <hip/hip_runtime.h>
#include <hip/hip_bf16.h>

typedef unsigned short u16;
typedef unsigned int u32;
typedef __attribute__((ext_vector_type(4))) float f32x4;
typedef __attribute__((ext_vector_type(8))) short short8;

#define DEV __device__ __forceinline__

// ---------- constants ----------
constexpr int Bc = 4, Tc = 64, Nc = 128, Dc = 256, Fc = 512;
constexpr int R = Bc * Tc * Nc;   // 32768 rows

// ---------- ws layout (bytes) ----------
constexpr size_t OFF_ABIN = 0;           // f32 [128*128]          65536
constexpr size_t OFF_DINV = 65536;       // f32 [128]              1024
constexpr size_t OFF_COLS = 66560;       // f32 [128]              1024
constexpr size_t OFF_AHT  = 67584;       // bf16 ahatT [c][r]      32768
constexpr size_t OFF_W1   = 100352;      // bf16 [3][1024][256]    1572864
constexpr size_t OFF_B1   = 1673216;     // f32 [3][1024]          12288
constexpr size_t OFF_GW   = 1685504;     // bf16 [2][512][512]     1048576
constexpr size_t OFF_CVEC = 2734080;     // f32 [2][512]           4096
constexpr size_t OFF_W2   = 2738176;     // bf16 [3][256][512]     786432
constexpr size_t OFF_BW   = 3524608;     // bf16 [256][768]        393216
constexpr size_t OFF_BTOT = 3917824;     // f32 [256]              1024
constexpr size_t OFF_CWT  = 3918848;     // bf16 cwA [64][192]     24576
constexpr size_t OFF_XHAT = 4194304;     // bf16 [R][256]          16777216
constexpr size_t OFF_U    = 20971520;    // bf16 [R][512]          33554432
constexpr size_t OFF_V    = 54525952;    // bf16 [R][512]          33554432
constexpr size_t OFF_S3   = 88080384;    // bf16 [R][512] / f32 [R][256]
constexpr size_t OFF_Y    = 121634816;   // bf16 [R][768]          50331648
constexpr size_t WS_NEED  = 171966464;

// ---------- helpers ----------
DEV u16 f2b(float f) { __hip_bfloat16 h = __float2bfloat16(f); return *(u16*)&h; }
DEV float b2f(u16 u) { union { u32 i; float f; } v; v.i = ((u32)u) << 16; return v.f; }
DEV u32 pack2(float a, float b) { return (u32)f2b(a) | ((u32)f2b(b) << 16); }
DEV float wave_sum(float s) {
  #pragma unroll
  for (int o = 32; o; o >>= 1) s += __shfl_xor(s, o);
  return s;
}
DEV float gelu(float v) { return 0.5f * v * (1.0f + erff(v * 0.70710678118654752f)); }
// direct global->LDS copy, 16 bytes per lane; LDS dest must be linear (base + lane*16)
DEV void gload16(const u16* g, u16* l) {
  __builtin_amdgcn_global_load_lds((const __attribute__((address_space(1))) void*)g,
                                   (__attribute__((address_space(3))) void*)l, 16, 0, 0);
}

// ---------- adjacency ----------
__global__ void k_adj1(const int* __restrict__ cir, float* __restrict__ aBin) {
  int r = blockIdx.x, c = threadIdx.x;
  aBin[r * 128 + c] = (cir[r * 128 + c] != 0 || r == c) ? 1.f : 0.f;
}
__global__ void k_adj2(const float* __restrict__ aBin, float* __restrict__ dinv) {
  int c = threadIdx.x; float s = 0.f;
  for (int r = 0; r < 128; r++) s += aBin[r * 128 + c];
  dinv[c] = rsqrtf(s);
}
// ahatT[c][r] = a_hat[r][c]
__global__ void k_adj3(const float* __restrict__ aBin, const float* __restrict__ dinv,
                       u16* __restrict__ ahatT) {
  int c = blockIdx.x, r = threadIdx.x;
  ahatT[c * 128 + r] = f2b(aBin[r * 128 + c] * dinv[r] * dinv[c]);
}
__global__ void k_adj4(const float* __restrict__ aBin, const float* __restrict__ dinv,
                       float* __restrict__ colsum) {
  int c = threadIdx.x; float s = 0.f;
  for (int r = 0; r < 128; r++) s += aBin[r * 128 + c] * dinv[r];
  colsum[c] = s * dinv[c];
}

// ---------- weight prep ----------
__global__ void k_prep_w1(const float* __restrict__ w1, const float* __restrict__ ng,
                          const float* __restrict__ nb, const float* __restrict__ b1,
                          u16* __restrict__ w1o, float* __restrict__ b1o) {
  int k = blockIdx.x, lane = threadIdx.x;
  float4 wv = *(const float4*)(w1 + k * 256 + lane * 4);
  float4 gv = *(const float4*)(ng + lane * 4);
  float4 bv = *(const float4*)(nb + lane * 4);
  uint2 o; o.x = pack2(wv.x * gv.x, wv.y * gv.y); o.y = pack2(wv.z * gv.z, wv.w * gv.w);
  *(uint2*)(w1o + k * 256 + lane * 4) = o;
  float acc = wv.x * bv.x + wv.y * bv.y + wv.z * bv.z + wv.w * bv.w;
  acc = wave_sum(acc);
  if (lane == 0) b1o[k] = b1[k] + acc;
}
__global__ void k_prep_gw(const float* __restrict__ gw, const float* __restrict__ sg,
                          const float* __restrict__ sb, u16* __restrict__ gwo,
                          float* __restrict__ cvo) {
  int f = blockIdx.x, lane = threadIdx.x;
  float acc = 0.f; uint4 o;
  float4 w0 = *(const float4*)(gw + f * 512 + lane * 8);
  float4 w1 = *(const float4*)(gw + f * 512 + lane * 8 + 4);
  float4 g0 = *(const float4*)(sg + lane * 8);
  float4 g1 = *(const float4*)(sg + lane * 8 + 4);
  float4 b0 = *(const float4*)(sb + lane * 8);
  float4 b1 = *(const float4*)(sb + lane * 8 + 4);
  o.x = pack2(w0.x * g0.x, w0.y * g0.y); o.y = pack2(w0.z * g0.z, w0.w * g0.w);
  o.z = pack2(w1.x * g1.x, w1.y * g1.y); o.w = pack2(w1.z * g1.z, w1.w * g1.w);
  acc = w0.x * b0.x + w0.y * b0.y + w0.z * b0.z + w0.w * b0.w
      + w1.x * b1.x + w1.y * b1.y + w1.z * b1.z + w1.w * b1.w;
  *(uint4*)(gwo + f * 512 + lane * 8) = o;
  acc = wave_sum(acc);
  if (lane == 0) cvo[f] = acc;
}
__global__ void k_b16cvt(const float* __restrict__ src, u16* __restrict__ dst) {
  int idx = (blockIdx.x * 64 + threadIdx.x) * 8;
  float4 a = *(const float4*)(src + idx);
  float4 b = *(const float4*)(src + idx + 4);
  uint4 o; o.x = pack2(a.x, a.y); o.y = pack2(a.z, a.w);
  o.z = pack2(b.x, b.y); o.w = pack2(b.z, b.w);
  *(uint4*)(dst + idx) = o;
}
__global__ void k_prep_wout(const float* __restrict__ wout, const float* __restrict__ bout,
                            const float* __restrict__ g1, const float* __restrict__ b1,
                            const float* __restrict__ g2, const float* __restrict__ b2,
                            const float* __restrict__ g3, const float* __restrict__ b3,
                            u16* __restrict__ bw, float* __restrict__ bt) {
  int o = blockIdx.x, lane = threadIdx.x;
  float acc = 0.f;
  #pragma unroll
  for (int j = 0; j < 12; j++) {
    int c = lane + j * 64;
    int p = c >> 8, i = c & 255;
    const float* gg = (p == 0) ? g1 : (p == 1) ? g2 : g3;
    const float* bb = (p == 0) ? b1 : (p == 1) ? b2 : b3;
    float w = wout[o * 768 + c];
    bw[o * 768 + c] = f2b(w * gg[i]);
    acc += w * bb[i];
  }
  acc = wave_sum(acc);
  if (lane == 0) bt[o] = bout[o] + acc;
}
// cwA[t][K] with K = tap*64 + ti, from cw[t][ti][0][tap]
__global__ void k_prep_cwA(const float* __restrict__ cw, u16* __restrict__ cwA) {
  int t = blockIdx.x, q = threadIdx.x;   // q = 0..191
  int tap = q >> 6, ti = q & 63;
  cwA[t * 192 + q] = f2b(cw[t * 192 + ti * 3 + tap]);
}

// ---------- LN kernels ----------
__global__ __launch_bounds__(256) void k_ln1(const float* __restrict__ x, u16* __restrict__ xhat) {
  int row = blockIdx.x * 4 + (threadIdx.x >> 6);
  int lane = threadIdx.x & 63;
  float4 v = *(const float4*)(x + (size_t)row * 256 + lane * 4);
  float s = v.x + v.y + v.z + v.w;
  float s2 = v.x * v.x + v.y * v.y + v.z * v.z + v.w * v.w;
  s = wave_sum(s); s2 = wave_sum(s2);
  float m = s * (1.f / 256.f);
  float var = s2 * (1.f / 256.f) - m * m;
  float rs = rsqrtf(var + 1e-5f);
  uint2 o; o.x = pack2((v.x - m) * rs, (v.y - m) * rs); o.y = pack2((v.z - m) * rs, (v.w - m) * rs);
  *(uint2*)(xhat + (size_t)row * 256 + lane * 4) = o;
}

template <int MODE>
__global__ __launch_bounds__(256) void k_lnv(const u16* __restrict__ Vin, u16* __restrict__ Vout,
                                             const float* __restrict__ sg, const float* __restrict__ sb) {
  int row = blockIdx.x * 4 + (threadIdx.x >> 6);
  int lane = threadIdx.x & 63;
  uint4 raw = *(const uint4*)(Vin + (size_t)row * 512 + lane * 8);
  u16* rp = (u16*)&raw;
  float f[8], s = 0.f, s2 = 0.f;
  #pragma unroll
  for (int j = 0; j < 8; j++) { f[j] = b2f(rp[j]); s += f[j]; s2 += f[j] * f[j]; }
  s = wave_sum(s); s2 = wave_sum(s2);
  float m = s * (1.f / 512.f);
  float var = s2 * (1.f / 512.f) - m * m;
  float rs = rsqrtf(var + 1e-5f);
  float o[8];
  if (MODE == 1) {
    float4 g0 = *(const float4*)(sg + lane * 8);
    float4 g1 = *(const float4*)(sg + lane * 8 + 4);
    float4 b0 = *(const float4*)(sb + lane * 8);
    float4 b1 = *(const float4*)(sb + lane * 8 + 4);
    o[0] = (f[0] - m) * rs * g0.x + b0.x; o[1] = (f[1] - m) * rs * g0.y + b0.y;
    o[2] = (f[2] - m) * rs * g0.z + b0.z; o[3] = (f[3] - m) * rs * g0.w + b0.w;
    o[4] = (f[4] - m) * rs * g1.x + b1.x; o[5] = (f[5] - m) * rs * g1.y + b1.y;
    o[6] = (f[6] - m) * rs * g1.z + b1.z; o[7] = (f[7] - m) * rs * g1.w + b1.w;
  } else {
    #pragma unroll
    for (int j = 0; j < 8; j++) o[j] = (f[j] - m) * rs;
  }
  uint4 ov; ov.x = pack2(o[0], o[1]); ov.y = pack2(o[2], o[3]);
  ov.z = pack2(o[4], o[5]); ov.w = pack2(o[6], o[7]);
  *(uint4*)(Vout + (size_t)row * 512 + lane * 8) = ov;
}

__global__ __launch_bounds__(256) void k_lny(const float* __restrict__ Y, u16* __restrict__ Ycat, int colofs) {
  int row = blockIdx.x * 4 + (threadIdx.x >> 6);
  int lane = threadIdx.x & 63;
  float4 v = *(const float4*)(Y + (size_t)row * 256 + lane * 4);
  float s = v.x + v.y + v.z + v.w;
  float s2 = v.x * v.x + v.y * v.y + v.z * v.z + v.w * v.w;
  s = wave_sum(s); s2 = wave_sum(s2);
  float m = s * (1.f / 256.f);
  float var = s2 * (1.f / 256.f) - m * m;
  float rs = rsqrtf(var + 1e-5f);
  uint2 o; o.x = pack2((v.x - m) * rs, (v.y - m) * rs); o.y = pack2((v.z - m) * rs, (v.w - m) * rs);
  *(uint2*)(Ycat + (size_t)row * 768 + colofs + lane * 4) = o;
}

// ---------- staging helper: direct global->LDS with source-side swizzle ----------
// Linear LDS slot qq=(row,kc) receives global k-group (kc ^ (row&7)); the compute-side
// XOR'd ds_read then yields the un-permuted data (XOR is an involution).
template <int KDIM>
DEV void stage_tile(const u16* __restrict__ G, u16* lds, int row0, int tid) {
  #pragma unroll
  for (int i = 0; i < 4; i++) {
    int qq = tid + i * 256;
    int row = qq >> 3, kc = qq & 7;
    int kg = kc ^ (row & 7);
    gload16(G + (size_t)(row0 + row) * KDIM + kg * 8, lds + qq * 8);
  }
}

// ---------- MFMA GEMM: C[M,ncols] = A[M,K] @ Bt[ncols,K]^T ----------
// EPI 0: gelu(acc+bias), split-store bf16: col<512 -> out0, else out1 (stride 512)
// EPI 2: acc + bias[col] + xres[row*256+col] -> f32 out0 (stride 256)
template <int KDIM, int EPI>
__global__ __launch_bounds__(256) void k_gemm(const u16* __restrict__ A, const u16* __restrict__ Bt,
                                              const float* __restrict__ bias,
                                              const float* __restrict__ xres,
                                              void* __restrict__ out0, void* __restrict__ out1) {
  __shared__ __align__(16) u16 As[128 * 64];
  __shared__ __align__(16) u16 Bs[128 * 64];
  const int tid = threadIdx.x;
  const int lane = tid & 63, wid = tid >> 6;
  const int wr = wid >> 1, wc = wid & 1;
  const int rowA0 = blockIdx.x * 128;
  const int colB0 = blockIdx.y * 128;

  f32x4 zero = {0.f, 0.f, 0.f, 0.f};
  f32x4 acc[4][4];
  #pragma unroll
  for (int m = 0; m < 4; m++)
    #pragma unroll
    for (int n = 0; n < 4; n++) acc[m][n] = zero;

  for (int k0 = 0; k0 < KDIM; k0 += 64) {
    stage_tile<KDIM>(A + k0, As, rowA0, tid);
    stage_tile<KDIM>(Bt + k0, Bs, colB0, tid);
    __syncthreads();
    #pragma unroll
    for (int kk = 0; kk < 2; kk++) {
      int kb = kk * 64 + (lane >> 4) * 16;
      short8 af[4], bfr[4];
      #pragma unroll
      for (int m = 0; m < 4; m++) {
        int row = wr * 64 + m * 16 + (lane & 15);
        af[m] = *(const short8*)((char*)As + ((row * 128 + kb) ^ ((row & 7) << 4)));
      }
      #pragma unroll
      for (int n = 0; n < 4; n++) {
        int col = wc * 64 + n * 16 + (lane & 15);
        bfr[n] = *(const short8*)((char*)Bs + ((col * 128 + kb) ^ ((col & 7) << 4)));
      }
      #pragma unroll
      for (int m = 0; m < 4; m++)
        #pragma unroll
        for (int n = 0; n < 4; n++)
          acc[m][n] = __builtin_amdgcn_mfma_f32_16x16x32_bf16(af[m], bfr[n], acc[m][n], 0, 0, 0);
    }
    __syncthreads();
  }

  #pragma unroll
  for (int m = 0; m < 4; m++) {
    #pragma unroll
    for (int n = 0; n < 4; n++) {
      int col = colB0 + wc * 64 + n * 16 + (lane & 15);
      #pragma unroll
      for (int r = 0; r < 4; r++) {
        int row = rowA0 + wr * 64 + m * 16 + (lane >> 4) * 4 + r;
        float v = acc[m][n][r];
        if (EPI == 0) {
          v = gelu(v + bias[col]);
          u16 hv = f2b(v);
          if (col < 512) ((u16*)out0)[(size_t)row * 512 + col] = hv;
          else           ((u16*)out1)[(size_t)row * 512 + col - 512] = hv;
        } else {
          v += bias[col] + xres[(size_t)row * 256 + col];
          ((float*)out0)[(size_t)row * 256 + col] = v;
        }
      }
    }
  }
}

// ---------- fused GCN: glin = A@GW^T (K=512), agg = ahatT@glin, ug = U*(agg + cs*cvec + gb) ----------
__global__ __launch_bounds__(256) void k_gcn(const u16* __restrict__ A, const u16* __restrict__ Bt,
                                             const u16* __restrict__ U, const u16* __restrict__ ahatT,
                                             const float* __restrict__ colsum, const float* __restrict__ cvec,
                                             const float* __restrict__ gb, u16* __restrict__ ug) {
  __shared__ __align__(16) char smem[34816];   // union: As+Bs (32768) / glinT 128x136 u16 (34816)
  u16* As = (u16*)smem;
  u16* Bs = (u16*)(smem + 16384);
  u16* glinT = (u16*)smem;
  const int tid = threadIdx.x;
  const int lane = tid & 63, wid = tid >> 6;
  const int wr = wid >> 1, wc = wid & 1;
  const int bt = blockIdx.x;
  const int rowA0 = bt * 128;
  const int colB0 = blockIdx.y * 128;

  f32x4 zero = {0.f, 0.f, 0.f, 0.f};
  f32x4 acc[4][4];
  #pragma unroll
  for (int m = 0; m < 4; m++)
    #pragma unroll
    for (int n = 0; n < 4; n++) acc[m][n] = zero;

  // ---- stage 1: glin tile [128 n][128 f] ----
  for (int k0 = 0; k0 < 512; k0 += 64) {
    stage_tile<512>(A + k0, As, rowA0, tid);
    stage_tile<512>(Bt + k0, Bs, colB0, tid);
    __syncthreads();
    #pragma unroll
    for (int kk = 0; kk < 2; kk++) {
      int kb = kk * 64 + (lane >> 4) * 16;
      short8 af[4], bfr[4];
      #pragma unroll
      for (int m = 0; m < 4; m++) {
        int row = wr * 64 + m * 16 + (lane & 15);
        af[m] = *(const short8*)((char*)As + ((row * 128 + kb) ^ ((row & 7) << 4)));
      }
      #pragma unroll
      for (int n = 0; n < 4; n++) {
        int col = wc * 64 + n * 16 + (lane & 15);
        bfr[n] = *(const short8*)((char*)Bs + ((col * 128 + kb) ^ ((col & 7) << 4)));
      }
      #pragma unroll
      for (int m = 0; m < 4; m++)
        #pragma unroll
        for (int n = 0; n < 4; n++)
          acc[m][n] = __builtin_amdgcn_mfma_f32_16x16x32_bf16(af[m], bfr[n], acc[m][n], 0, 0, 0);
    }
    __syncthreads();
  }

  // ---- write glinT[f][n] (bf16, pad 136) ----
  #pragma unroll
  for (int m = 0; m < 4; m++) {
    #pragma unroll
    for (int n = 0; n < 4; n++) {
      int f = wc * 64 + n * 16 + (lane & 15);
      int n0 = wr * 64 + m * 16 + (lane >> 4) * 4;
      u32* p = (u32*)(glinT + f * 136 + n0);
      p[0] = pack2(acc[m][n][0], acc[m][n][1]);
      p[1] = pack2(acc[m][n][2], acc[m][n][3]);
    }
  }
  __syncthreads();

  // ---- stage 2: C2[c][f] = sum_r ahatT[c][r] * glin[r][f] ----
  f32x4 acc2[4][4];
  #pragma unroll
  for (int m = 0; m < 4; m++)
    #pragma unroll
    for (int n = 0; n < 4; n++) acc2[m][n] = zero;
  #pragma unroll
  for (int ks = 0; ks < 4; ks++) {
    short8 a2[4], b2v[4];
    #pragma unroll
    for (int m = 0; m < 4; m++) {
      int c = wr * 64 + m * 16 + (lane & 15);
      a2[m] = *(const short8*)(ahatT + c * 128 + ks * 32 + (lane >> 4) * 8);
    }
    #pragma unroll
    for (int n = 0; n < 4; n++) {
      int f = wc * 64 + n * 16 + (lane & 15);
      b2v[n] = *(const short8*)(glinT + f * 136 + ks * 32 + (lane >> 4) * 8);
    }
    #pragma unroll
    for (int m = 0; m < 4; m++)
      #pragma unroll
      for (int n = 0; n < 4; n++)
        acc2[m][n] = __builtin_amdgcn_mfma_f32_16x16x32_bf16(a2[m], b2v[n], acc2[m][n], 0, 0, 0);
  }

  // ---- epilogue: ug = U * (acc2 + colsum[c]*cvec[f] + gb[f]) ----
  #pragma unroll
  for (int m = 0; m < 4; m++) {
    #pragma unroll
    for (int n = 0; n < 4; n++) {
      int fl = wc * 64 + n * 16 + (lane & 15);
      int fg = colB0 + fl;
      float cv = cvec[fg], gbv = gb[fg];
      #pragma unroll
      for (int r = 0; r < 4; r++) {
        int c = wr * 64 + m * 16 + (lane >> 4) * 4 + r;
        size_t row = (size_t)(rowA0 + c) * 512 + fg;
        float g = b2f(U[row]) * (acc2[m][n][r] + colsum[c] * cv + gbv);
        ug[row] = f2b(g);
      }
    }
  }
}

// ---------- MFMA conv: out[t,f] = sum_tap sum_ti cwA[t][tap*64+ti]*vn[ti][f+tap-1]; ug = U*(out+cb) ----------
__global__ __launch_bounds__(256) void k_convm(const u16* __restrict__ vn, const u16* __restrict__ U,
                                               const u16* __restrict__ cwA, const float* __restrict__ cb,
                                               u16* __restrict__ ug) {
  __shared__ __align__(16) u16 vnT[258 * 72];   // [vrow = f_local + tap][ti], pad 72
  int bx = blockIdx.x;
  int n = bx & 127, b = (bx >> 7) & 3, h = bx >> 9;
  int tid = threadIdx.x;
  int lane = tid & 63, wid = tid >> 6;

  {
    int ti = tid & 63;
    size_t rowbase = ((size_t)((b * 64 + ti) * 128 + n)) * 512;
    #pragma unroll
    for (int it = 0; it < 8; it++) {
      int fq = (tid >> 6) + it * 4;   // 0..31
      uint4 raw = *(const uint4*)(vn + rowbase + h * 256 + fq * 8);
      u16* rp = (u16*)&raw;
      int vr = fq * 8 + 1;
      #pragma unroll
      for (int j = 0; j < 8; j++) vnT[(vr + j) * 72 + ti] = rp[j];
    }
    if (tid < 64) {
      vnT[0 * 72 + ti]   = (h == 0) ? (u16)0 : vn[rowbase + 255];
      vnT[257 * 72 + ti] = (h == 1) ? (u16)0 : vn[rowbase + 256];
    }
  }
  __syncthreads();

  f32x4 zero = {0.f, 0.f, 0.f, 0.f};
  f32x4 acc[4][4];
  #pragma unroll
  for (int m = 0; m < 4; m++)
    #pragma unroll
    for (int nn = 0; nn < 4; nn++) acc[m][nn] = zero;

  #pragma unroll
  for (int s = 0; s < 6; s++) {
    int tap = s >> 1;
    int K0 = s * 32;
    int tig = (s & 1) * 32 + (lane >> 4) * 8;
    short8 af[4], bf[4];
    #pragma unroll
    for (int m = 0; m < 4; m++) {
      int t = m * 16 + (lane & 15);
      af[m] = *(const short8*)(cwA + t * 192 + K0 + (lane >> 4) * 8);
    }
    #pragma unroll
    for (int nn = 0; nn < 4; nn++) {
      int fl = wid * 64 + nn * 16 + (lane & 15);
      int vr = fl + tap;
      bf[nn] = *(const short8*)(vnT + vr * 72 + tig);
    }
    #pragma unroll
    for (int m = 0; m < 4; m++)
      #pragma unroll
      for (int nn = 0; nn < 4; nn++)
        acc[m][nn] = __builtin_amdgcn_mfma_f32_16x16x32_bf16(af[m], bf[nn], acc[m][nn], 0, 0, 0);
  }

  #pragma unroll
  for (int m = 0; m < 4; m++) {
    #pragma unroll
    for (int nn = 0; nn < 4; nn++) {
      int fl = wid * 64 + nn * 16 + (lane & 15);
      int fg = h * 256 + fl;
      #pragma unroll
      for (int r = 0; r < 4; r++) {
        int t = m * 16 + (lane >> 4) * 4 + r;
        size_t row = ((size_t)((b * 64 + t) * 128 + n)) * 512 + fg;
        float g = b2f(U[row]) * (acc[m][nn][r] + cb[t]);
        ug[row] = f2b(g);
      }
    }
  }
}

// ---------- launch ----------
extern "C" void kernel_launch(void* const* d_in, const int* in_sizes, int n_in,
                              void* d_out, int out_size, void* d_ws, size_t ws_size,
                              hipStream_t stream) {
  if (ws_size < WS_NEED) return;
  const float* x = (const float*)d_in[0];
  const int* cir = (const int*)d_in[1];
  auto F32 = [&](int i) { return (const float*)d_in[i]; };

  char* W = (char*)d_ws;
  float* aBin   = (float*)(W + OFF_ABIN);
  float* dinv   = (float*)(W + OFF_DINV);
  float* colsum = (float*)(W + OFF_COLS);
  u16*   ahatT  = (u16*)(W + OFF_AHT);
  u16*   W1c    = (u16*)(W + OFF_W1);
  float* b1c    = (float*)(W + OFF_B1);
  u16*   GWc    = (u16*)(W + OFF_GW);
  float* cvec   = (float*)(W + OFF_CVEC);
  u16*   W2c    = (u16*)(W + OFF_W2);
  u16*   BW     = (u16*)(W + OFF_BW);
  float* btot   = (float*)(W + OFF_BTOT);
  u16*   cwA    = (u16*)(W + OFF_CWT);
  u16*   xhat   = (u16*)(W + OFF_XHAT);
  u16*   Ub     = (u16*)(W + OFF_U);
  u16*   Vb     = (u16*)(W + OFF_V);
  u16*   S3     = (u16*)(W + OFF_S3);
  u16*   Ycat   = (u16*)(W + OFF_Y);

  // prep
  k_adj1<<<128, 128, 0, stream>>>(cir, aBin);
  k_adj2<<<1, 128, 0, stream>>>(aBin, dinv);
  k_adj3<<<128, 128, 0, stream>>>(aBin, dinv, ahatT);
  k_adj4<<<1, 128, 0, stream>>>(aBin, dinv, colsum);
  for (int p = 0; p < 3; p++) {
    int base = 2 + 8 * p;
    k_prep_w1<<<1024, 64, 0, stream>>>(F32(base + 2), F32(base + 0), F32(base + 1), F32(base + 3),
                                       W1c + (size_t)p * 1024 * 256, b1c + p * 1024);
    k_b16cvt<<<256, 64, 0, stream>>>(F32(base + 6), W2c + (size_t)p * 256 * 512);
  }
  k_prep_gw<<<512, 64, 0, stream>>>(F32(28), F32(14), F32(15), GWc, cvec);
  k_prep_gw<<<512, 64, 0, stream>>>(F32(30), F32(22), F32(23), GWc + 512 * 512, cvec + 512);
  k_prep_wout<<<256, 64, 0, stream>>>(F32(38), F32(39), F32(32), F32(33), F32(34), F32(35),
                                      F32(36), F32(37), BW, btot);
  k_prep_cwA<<<64, 192, 0, stream>>>(F32(26), cwA);

  // shared LN(x)
  k_ln1<<<8192, 256, 0, stream>>>(x, xhat);

  // ---- branch t (conv) ----
  k_gemm<256, 0><<<dim3(256, 8), 256, 0, stream>>>(xhat, W1c, b1c, nullptr, Ub, Vb);
  k_lnv<1><<<8192, 256, 0, stream>>>(Vb, S3, F32(6), F32(7));
  k_convm<<<1024, 256, 0, stream>>>(S3, Ub, cwA, F32(27), Vb);
  k_gemm<512, 2><<<dim3(256, 2), 256, 0, stream>>>(Vb, W2c, F32(9), x, (void*)S3, nullptr);
  k_lny<<<8192, 256, 0, stream>>>((const float*)S3, Ycat, 0);

  // ---- branch s (GCN) ----
  k_gemm<256, 0><<<dim3(256, 8), 256, 0, stream>>>(xhat, W1c + (size_t)1 * 1024 * 256, b1c + 1024,
                                                   nullptr, Ub, Vb);
  k_lnv<0><<<8192, 256, 0, stream>>>(Vb, S3, nullptr, nullptr);
  k_gcn<<<dim3(256, 4), 256, 0, stream>>>(S3, GWc, Ub, ahatT, colsum, cvec, F32(29), Vb);
  k_gemm<512, 2><<<dim3(256, 2), 256, 0, stream>>>(Vb, W2c + (size_t)1 * 256 * 512, F32(17), x,
                                                   (void*)S3, nullptr);
  k_lny<<<8192, 256, 0, stream>>>((const float*)S3, Ycat, 256);

  // ---- branch c (GCN) ----
  k_gemm<256, 0><<<dim3(256, 8), 256, 0, stream>>>(xhat, W1c + (size_t)2 * 1024 * 256, b1c + 2048,
                                                   nullptr, Ub, Vb);
  k_lnv<0><<<8192, 256, 0, stream>>>(Vb, S3, nullptr, nullptr);
  k_gcn<<<dim3(256, 4), 256, 0, stream>>>(S3, GWc + 512 * 512, Ub, ahatT, colsum, cvec + 512, F32(31), Vb);
  k_gemm<512, 2><<<dim3(256, 2), 256, 0, stream>>>(Vb, W2c + (size_t)2 * 256 * 512, F32(25), x,
                                                   (void*)S3, nullptr);
  k_lny<<<8192, 256, 0, stream>>>((const float*)S3, Ycat, 512);

  // ---- final projection ----
  k_gemm<768, 2><<<dim3(256, 2), 256, 0, stream>>>(Ycat, BW, btot, x, d_out, nullptr);
}

// Round 5
// 595.011 us; speedup vs baseline: 1.5366x; 1.0219x over previous
//
#include <hip/hip_runtime.h>
#include <hip/hip_bf16.h>

typedef unsigned short u16;
typedef unsigned int u32;
typedef __attribute__((ext_vector_type(4))) float f32x4;
typedef __attribute__((ext_vector_type(8))) short short8;

#define DEV __device__ __forceinline__

// ---------- constants ----------
constexpr int Bc = 4, Tc = 64, Nc = 128, Dc = 256, Fc = 512;
constexpr int R = Bc * Tc * Nc;   // 32768 rows

// ---------- ws layout (bytes) ----------
constexpr size_t OFF_ABIN = 0;           // f32 [128*128]          65536
constexpr size_t OFF_DINV = 65536;       // f32 [128]              1024
constexpr size_t OFF_COLS = 66560;       // f32 [128]              1024
constexpr size_t OFF_AHT  = 67584;       // bf16 ahatT [c][r]      32768
constexpr size_t OFF_W1   = 100352;      // bf16 [3][1024][256]    1572864
constexpr size_t OFF_B1   = 1673216;     // f32 [3][1024]          12288
constexpr size_t OFF_GW   = 1685504;     // bf16 [2][512][512]     1048576
constexpr size_t OFF_CVEC = 2734080;     // f32 [2][512]           4096
constexpr size_t OFF_W2   = 2738176;     // bf16 [3][256][512]     786432
constexpr size_t OFF_BW   = 3524608;     // bf16 [256][768]        393216
constexpr size_t OFF_BTOT = 3917824;     // f32 [256]              1024
constexpr size_t OFF_CWT  = 3918848;     // bf16 cwA [64][192]     24576
constexpr size_t OFF_XHAT = 4194304;     // bf16 [R][256]          16777216
constexpr size_t OFF_U    = 20971520;    // bf16 [R][512]          33554432
constexpr size_t OFF_V    = 54525952;    // bf16 [R][512]          33554432
constexpr size_t OFF_S3   = 88080384;    // bf16 [R][512] / f32 [R][256]
constexpr size_t OFF_Y    = 121634816;   // bf16 [R][768]          50331648
constexpr size_t WS_NEED  = 171966464;

// ---------- helpers ----------
DEV u16 f2b(float f) { __hip_bfloat16 h = __float2bfloat16(f); return *(u16*)&h; }
DEV float b2f(u16 u) { union { u32 i; float f; } v; v.i = ((u32)u) << 16; return v.f; }
DEV u32 pack2(float a, float b) { return (u32)f2b(a) | ((u32)f2b(b) << 16); }
DEV float wave_sum(float s) {
  #pragma unroll
  for (int o = 32; o; o >>= 1) s += __shfl_xor(s, o);
  return s;
}
// tanh-approx gelu: 0.5x(1+tanh(sqrt(2/pi)(x+0.044715x^3))) = x - x/(e+1), e=exp(2c(x+0.044715x^3))
// branch-free, NaN-safe at +/-inf; |err| vs exact-erf gelu <= ~2e-3 (absorbed by bf16 rounding downstream)
DEV float gelu(float v) {
  float t = v * v;
  float e = __expf(v * (1.5957691f + 0.0713548162f * t));
  return v - v * __builtin_amdgcn_rcpf(e + 1.0f);
}
// direct global->LDS copy, 16 bytes per lane; LDS dest must be linear (base + lane*16)
DEV void gload16(const u16* g, u16* l) {
  __builtin_amdgcn_global_load_lds((const __attribute__((address_space(1))) void*)g,
                                   (__attribute__((address_space(3))) void*)l, 16, 0, 0);
}
DEV void wait_vm0()   { asm volatile("s_waitcnt vmcnt(0)" ::: "memory");  __builtin_amdgcn_sched_barrier(0); }
DEV void wait_lgkm0() { asm volatile("s_waitcnt lgkmcnt(0)" ::: "memory"); __builtin_amdgcn_sched_barrier(0); }

// ---------- adjacency ----------
__global__ void k_adj1(const int* __restrict__ cir, float* __restrict__ aBin) {
  int r = blockIdx.x, c = threadIdx.x;
  aBin[r * 128 + c] = (cir[r * 128 + c] != 0 || r == c) ? 1.f : 0.f;
}
__global__ void k_adj2(const float* __restrict__ aBin, float* __restrict__ dinv) {
  int c = threadIdx.x; float s = 0.f;
  for (int r = 0; r < 128; r++) s += aBin[r * 128 + c];
  dinv[c] = rsqrtf(s);
}
// ahatT[c][r] = a_hat[r][c]
__global__ void k_adj3(const float* __restrict__ aBin, const float* __restrict__ dinv,
                       u16* __restrict__ ahatT) {
  int c = blockIdx.x, r = threadIdx.x;
  ahatT[c * 128 + r] = f2b(aBin[r * 128 + c] * dinv[r] * dinv[c]);
}
__global__ void k_adj4(const float* __restrict__ aBin, const float* __restrict__ dinv,
                       float* __restrict__ colsum) {
  int c = threadIdx.x; float s = 0.f;
  for (int r = 0; r < 128; r++) s += aBin[r * 128 + c] * dinv[r];
  colsum[c] = s * dinv[c];
}

// ---------- weight prep ----------
__global__ void k_prep_w1(const float* __restrict__ w1, const float* __restrict__ ng,
                          const float* __restrict__ nb, const float* __restrict__ b1,
                          u16* __restrict__ w1o, float* __restrict__ b1o) {
  int k = blockIdx.x, lane = threadIdx.x;
  float4 wv = *(const float4*)(w1 + k * 256 + lane * 4);
  float4 gv = *(const float4*)(ng + lane * 4);
  float4 bv = *(const float4*)(nb + lane * 4);
  uint2 o; o.x = pack2(wv.x * gv.x, wv.y * gv.y); o.y = pack2(wv.z * gv.z, wv.w * gv.w);
  *(uint2*)(w1o + k * 256 + lane * 4) = o;
  float acc = wv.x * bv.x + wv.y * bv.y + wv.z * bv.z + wv.w * bv.w;
  acc = wave_sum(acc);
  if (lane == 0) b1o[k] = b1[k] + acc;
}
__global__ void k_prep_gw(const float* __restrict__ gw, const float* __restrict__ sg,
                          const float* __restrict__ sb, u16* __restrict__ gwo,
                          float* __restrict__ cvo) {
  int f = blockIdx.x, lane = threadIdx.x;
  float acc = 0.f; uint4 o;
  float4 w0 = *(const float4*)(gw + f * 512 + lane * 8);
  float4 w1 = *(const float4*)(gw + f * 512 + lane * 8 + 4);
  float4 g0 = *(const float4*)(sg + lane * 8);
  float4 g1 = *(const float4*)(sg + lane * 8 + 4);
  float4 b0 = *(const float4*)(sb + lane * 8);
  float4 b1 = *(const float4*)(sb + lane * 8 + 4);
  o.x = pack2(w0.x * g0.x, w0.y * g0.y); o.y = pack2(w0.z * g0.z, w0.w * g0.w);
  o.z = pack2(w1.x * g1.x, w1.y * g1.y); o.w = pack2(w1.z * g1.z, w1.w * g1.w);
  acc = w0.x * b0.x + w0.y * b0.y + w0.z * b0.z + w0.w * b0.w
      + w1.x * b1.x + w1.y * b1.y + w1.z * b1.z + w1.w * b1.w;
  *(uint4*)(gwo + f * 512 + lane * 8) = o;
  acc = wave_sum(acc);
  if (lane == 0) cvo[f] = acc;
}
__global__ void k_b16cvt(const float* __restrict__ src, u16* __restrict__ dst) {
  int idx = (blockIdx.x * 64 + threadIdx.x) * 8;
  float4 a = *(const float4*)(src + idx);
  float4 b = *(const float4*)(src + idx + 4);
  uint4 o; o.x = pack2(a.x, a.y); o.y = pack2(a.z, a.w);
  o.z = pack2(b.x, b.y); o.w = pack2(b.z, b.w);
  *(uint4*)(dst + idx) = o;
}
__global__ void k_prep_wout(const float* __restrict__ wout, const float* __restrict__ bout,
                            const float* __restrict__ g1, const float* __restrict__ b1,
                            const float* __restrict__ g2, const float* __restrict__ b2,
                            const float* __restrict__ g3, const float* __restrict__ b3,
                            u16* __restrict__ bw, float* __restrict__ bt) {
  int o = blockIdx.x, lane = threadIdx.x;
  float acc = 0.f;
  #pragma unroll
  for (int j = 0; j < 12; j++) {
    int c = lane + j * 64;
    int p = c >> 8, i = c & 255;
    const float* gg = (p == 0) ? g1 : (p == 1) ? g2 : g3;
    const float* bb = (p == 0) ? b1 : (p == 1) ? b2 : b3;
    float w = wout[o * 768 + c];
    bw[o * 768 + c] = f2b(w * gg[i]);
    acc += w * bb[i];
  }
  acc = wave_sum(acc);
  if (lane == 0) bt[o] = bout[o] + acc;
}
// cwA[t][K] with K = tap*64 + ti, from cw[t][ti][0][tap]
__global__ void k_prep_cwA(const float* __restrict__ cw, u16* __restrict__ cwA) {
  int t = blockIdx.x, q = threadIdx.x;   // q = 0..191
  int tap = q >> 6, ti = q & 63;
  cwA[t * 192 + q] = f2b(cw[t * 192 + ti * 3 + tap]);
}

// ---------- LN kernels ----------
__global__ __launch_bounds__(256) void k_ln1(const float* __restrict__ x, u16* __restrict__ xhat) {
  int row = blockIdx.x * 4 + (threadIdx.x >> 6);
  int lane = threadIdx.x & 63;
  float4 v = *(const float4*)(x + (size_t)row * 256 + lane * 4);
  float s = v.x + v.y + v.z + v.w;
  float s2 = v.x * v.x + v.y * v.y + v.z * v.z + v.w * v.w;
  s = wave_sum(s); s2 = wave_sum(s2);
  float m = s * (1.f / 256.f);
  float var = s2 * (1.f / 256.f) - m * m;
  float rs = rsqrtf(var + 1e-5f);
  uint2 o; o.x = pack2((v.x - m) * rs, (v.y - m) * rs); o.y = pack2((v.z - m) * rs, (v.w - m) * rs);
  *(uint2*)(xhat + (size_t)row * 256 + lane * 4) = o;
}

template <int MODE>
__global__ __launch_bounds__(256) void k_lnv(const u16* __restrict__ Vin, u16* __restrict__ Vout,
                                             const float* __restrict__ sg, const float* __restrict__ sb) {
  int row = blockIdx.x * 4 + (threadIdx.x >> 6);
  int lane = threadIdx.x & 63;
  uint4 raw = *(const uint4*)(Vin + (size_t)row * 512 + lane * 8);
  u16* rp = (u16*)&raw;
  float f[8], s = 0.f, s2 = 0.f;
  #pragma unroll
  for (int j = 0; j < 8; j++) { f[j] = b2f(rp[j]); s += f[j]; s2 += f[j] * f[j]; }
  s = wave_sum(s); s2 = wave_sum(s2);
  float m = s * (1.f / 512.f);
  float var = s2 * (1.f / 512.f) - m * m;
  float rs = rsqrtf(var + 1e-5f);
  float o[8];
  if (MODE == 1) {
    float4 g0 = *(const float4*)(sg + lane * 8);
    float4 g1 = *(const float4*)(sg + lane * 8 + 4);
    float4 b0 = *(const float4*)(sb + lane * 8);
    float4 b1 = *(const float4*)(sb + lane * 8 + 4);
    o[0] = (f[0] - m) * rs * g0.x + b0.x; o[1] = (f[1] - m) * rs * g0.y + b0.y;
    o[2] = (f[2] - m) * rs * g0.z + b0.z; o[3] = (f[3] - m) * rs * g0.w + b0.w;
    o[4] = (f[4] - m) * rs * g1.x + b1.x; o[5] = (f[5] - m) * rs * g1.y + b1.y;
    o[6] = (f[6] - m) * rs * g1.z + b1.z; o[7] = (f[7] - m) * rs * g1.w + b1.w;
  } else {
    #pragma unroll
    for (int j = 0; j < 8; j++) o[j] = (f[j] - m) * rs;
  }
  uint4 ov; ov.x = pack2(o[0], o[1]); ov.y = pack2(o[2], o[3]);
  ov.z = pack2(o[4], o[5]); ov.w = pack2(o[6], o[7]);
  *(uint4*)(Vout + (size_t)row * 512 + lane * 8) = ov;
}

__global__ __launch_bounds__(256) void k_lny(const float* __restrict__ Y, u16* __restrict__ Ycat, int colofs) {
  int row = blockIdx.x * 4 + (threadIdx.x >> 6);
  int lane = threadIdx.x & 63;
  float4 v = *(const float4*)(Y + (size_t)row * 256 + lane * 4);
  float s = v.x + v.y + v.z + v.w;
  float s2 = v.x * v.x + v.y * v.y + v.z * v.z + v.w * v.w;
  s = wave_sum(s); s2 = wave_sum(s2);
  float m = s * (1.f / 256.f);
  float var = s2 * (1.f / 256.f) - m * m;
  float rs = rsqrtf(var + 1e-5f);
  uint2 o; o.x = pack2((v.x - m) * rs, (v.y - m) * rs); o.y = pack2((v.z - m) * rs, (v.w - m) * rs);
  *(uint2*)(Ycat + (size_t)row * 768 + colofs + lane * 4) = o;
}

// ---------- staging helper: direct global->LDS with source-side swizzle ----------
// Linear LDS slot qq=(row,kc) receives global k-group (kc ^ (row&7)); the compute-side
// XOR'd ds_read then yields the un-permuted data (XOR is an involution).
template <int KDIM>
DEV void stage_tile(const u16* __restrict__ G, u16* lds, int row0, int tid) {
  #pragma unroll
  for (int i = 0; i < 4; i++) {
    int qq = tid + i * 256;
    int row = qq >> 3, kc = qq & 7;
    int kg = kc ^ (row & 7);
    gload16(G + (size_t)(row0 + row) * KDIM + kg * 8, lds + qq * 8);
  }
}

// one 64-wide K-step of MFMA on a staged tile pair
DEV void mfma_step(const u16* As, const u16* Bs, f32x4 (&acc)[4][4], int lane, int wr, int wc) {
  #pragma unroll
  for (int kk = 0; kk < 2; kk++) {
    int kb = kk * 64 + (lane >> 4) * 16;
    short8 af[4], bfr[4];
    #pragma unroll
    for (int m = 0; m < 4; m++) {
      int row = wr * 64 + m * 16 + (lane & 15);
      af[m] = *(const short8*)((const char*)As + ((row * 128 + kb) ^ ((row & 7) << 4)));
    }
    #pragma unroll
    for (int n = 0; n < 4; n++) {
      int col = wc * 64 + n * 16 + (lane & 15);
      bfr[n] = *(const short8*)((const char*)Bs + ((col * 128 + kb) ^ ((col & 7) << 4)));
    }
    #pragma unroll
    for (int m = 0; m < 4; m++)
      #pragma unroll
      for (int n = 0; n < 4; n++)
        acc[m][n] = __builtin_amdgcn_mfma_f32_16x16x32_bf16(af[m], bfr[n], acc[m][n], 0, 0, 0);
  }
}

// ---------- MFMA GEMM: C[M,ncols] = A[M,K] @ Bt[ncols,K]^T ----------
// 2-phase double-buffered staging (T3 minimum recipe): stage next tile before computing
// current; one {lgkmcnt(0); vmcnt(0); s_barrier} per tile (raw barrier, no full drain
// at stage-issue time). EPI 0: gelu(acc+bias) split-store bf16. EPI 2: +bias+res f32.
template <int KDIM, int EPI>
__global__ __launch_bounds__(256) void k_gemm(const u16* __restrict__ A, const u16* __restrict__ Bt,
                                              const float* __restrict__ bias,
                                              const float* __restrict__ xres,
                                              void* __restrict__ out0, void* __restrict__ out1) {
  __shared__ __align__(16) u16 lds[4 * 8192];   // As0 Bs0 As1 Bs1 (16KB each)
  u16* As[2] = { lds, lds + 16384 };
  u16* Bs[2] = { lds + 8192, lds + 24576 };
  const int tid = threadIdx.x;
  const int lane = tid & 63, wid = tid >> 6;
  const int wr = wid >> 1, wc = wid & 1;
  const int rowA0 = blockIdx.x * 128;
  const int colB0 = blockIdx.y * 128;
  constexpr int NT = KDIM / 64;

  f32x4 zero = {0.f, 0.f, 0.f, 0.f};
  f32x4 acc[4][4];
  #pragma unroll
  for (int m = 0; m < 4; m++)
    #pragma unroll
    for (int n = 0; n < 4; n++) acc[m][n] = zero;

  // prologue: stage tile 0, drain, barrier
  stage_tile<KDIM>(A, As[0], rowA0, tid);
  stage_tile<KDIM>(Bt, Bs[0], colB0, tid);
  wait_vm0();
  __builtin_amdgcn_s_barrier();

  #pragma unroll
  for (int it = 0; it < NT; ++it) {
    const int cur = it & 1;
    if (it + 1 < NT) {
      stage_tile<KDIM>(A + (it + 1) * 64, As[cur ^ 1], rowA0, tid);
      stage_tile<KDIM>(Bt + (it + 1) * 64, Bs[cur ^ 1], colB0, tid);
    }
    mfma_step(As[cur], Bs[cur], acc, lane, wr, wc);
    wait_lgkm0();           // all my ds_reads of buf[cur] landed (safe to overwrite next iter)
    wait_vm0();             // next tile fully in LDS (latency hidden under MFMA above)
    __builtin_amdgcn_s_barrier();
  }

  #pragma unroll
  for (int m = 0; m < 4; m++) {
    #pragma unroll
    for (int n = 0; n < 4; n++) {
      int col = colB0 + wc * 64 + n * 16 + (lane & 15);
      #pragma unroll
      for (int r = 0; r < 4; r++) {
        int row = rowA0 + wr * 64 + m * 16 + (lane >> 4) * 4 + r;
        float v = acc[m][n][r];
        if (EPI == 0) {
          v = gelu(v + bias[col]);
          u16 hv = f2b(v);
          if (col < 512) ((u16*)out0)[(size_t)row * 512 + col] = hv;
          else           ((u16*)out1)[(size_t)row * 512 + col - 512] = hv;
        } else {
          v += bias[col] + xres[(size_t)row * 256 + col];
          ((float*)out0)[(size_t)row * 256 + col] = v;
        }
      }
    }
  }
}

// ---------- fused GCN: glin = A@GW^T (K=512), agg = ahatT@glin, ug = U*(agg + cs*cvec + gb) ----------
__global__ __launch_bounds__(256) void k_gcn(const u16* __restrict__ A, const u16* __restrict__ Bt,
                                             const u16* __restrict__ U, const u16* __restrict__ ahatT,
                                             const float* __restrict__ colsum, const float* __restrict__ cvec,
                                             const float* __restrict__ gb, u16* __restrict__ ug) {
  __shared__ __align__(16) char smem[65536];   // dbuf staging (64KB) / glinT 128x136 u16 (34.8KB)
  u16* As[2] = { (u16*)smem, (u16*)(smem + 32768) };
  u16* Bs[2] = { (u16*)(smem + 16384), (u16*)(smem + 49152) };
  u16* glinT = (u16*)smem;
  const int tid = threadIdx.x;
  const int lane = tid & 63, wid = tid >> 6;
  const int wr = wid >> 1, wc = wid & 1;
  const int bt = blockIdx.x;
  const int rowA0 = bt * 128;
  const int colB0 = blockIdx.y * 128;

  f32x4 zero = {0.f, 0.f, 0.f, 0.f};
  f32x4 acc[4][4];
  #pragma unroll
  for (int m = 0; m < 4; m++)
    #pragma unroll
    for (int n = 0; n < 4; n++) acc[m][n] = zero;

  // ---- stage 1: glin tile [128 n][128 f], 2-phase pipelined ----
  stage_tile<512>(A, As[0], rowA0, tid);
  stage_tile<512>(Bt, Bs[0], colB0, tid);
  wait_vm0();
  __builtin_amdgcn_s_barrier();
  #pragma unroll
  for (int it = 0; it < 8; ++it) {
    const int cur = it & 1;
    if (it + 1 < 8) {
      stage_tile<512>(A + (it + 1) * 64, As[cur ^ 1], rowA0, tid);
      stage_tile<512>(Bt + (it + 1) * 64, Bs[cur ^ 1], colB0, tid);
    }
    mfma_step(As[cur], Bs[cur], acc, lane, wr, wc);
    wait_lgkm0();
    wait_vm0();
    __builtin_amdgcn_s_barrier();
  }

  // ---- write glinT[f][n] (bf16, pad 136) ----
  #pragma unroll
  for (int m = 0; m < 4; m++) {
    #pragma unroll
    for (int n = 0; n < 4; n++) {
      int f = wc * 64 + n * 16 + (lane & 15);
      int n0 = wr * 64 + m * 16 + (lane >> 4) * 4;
      u32* p = (u32*)(glinT + f * 136 + n0);
      p[0] = pack2(acc[m][n][0], acc[m][n][1]);
      p[1] = pack2(acc[m][n][2], acc[m][n][3]);
    }
  }
  __syncthreads();

  // ---- stage 2: C2[c][f] = sum_r ahatT[c][r] * glin[r][f] ----
  f32x4 acc2[4][4];
  #pragma unroll
  for (int m = 0; m < 4; m++)
    #pragma unroll
    for (int n = 0; n < 4; n++) acc2[m][n] = zero;
  #pragma unroll
  for (int ks = 0; ks < 4; ks++) {
    short8 a2[4], b2v[4];
    #pragma unroll
    for (int m = 0; m < 4; m++) {
      int c = wr * 64 + m * 16 + (lane & 15);
      a2[m] = *(const short8*)(ahatT + c * 128 + ks * 32 + (lane >> 4) * 8);
    }
    #pragma unroll
    for (int n = 0; n < 4; n++) {
      int f = wc * 64 + n * 16 + (lane & 15);
      b2v[n] = *(const short8*)(glinT + f * 136 + ks * 32 + (lane >> 4) * 8);
    }
    #pragma unroll
    for (int m = 0; m < 4; m++)
      #pragma unroll
      for (int n = 0; n < 4; n++)
        acc2[m][n] = __builtin_amdgcn_mfma_f32_16x16x32_bf16(a2[m], b2v[n], acc2[m][n], 0, 0, 0);
  }

  // ---- epilogue: ug = U * (acc2 + colsum[c]*cvec[f] + gb[f]) ----
  #pragma unroll
  for (int m = 0; m < 4; m++) {
    #pragma unroll
    for (int n = 0; n < 4; n++) {
      int fl = wc * 64 + n * 16 + (lane & 15);
      int fg = colB0 + fl;
      float cv = cvec[fg], gbv = gb[fg];
      #pragma unroll
      for (int r = 0; r < 4; r++) {
        int c = wr * 64 + m * 16 + (lane >> 4) * 4 + r;
        size_t row = (size_t)(rowA0 + c) * 512 + fg;
        float g = b2f(U[row]) * (acc2[m][n][r] + colsum[c] * cv + gbv);
        ug[row] = f2b(g);
      }
    }
  }
}

// ---------- MFMA conv: out[t,f] = sum_tap sum_ti cwA[t][tap*64+ti]*vn[ti][f+tap-1]; ug = U*(out+cb) ----------
__global__ __launch_bounds__(256) void k_convm(const u16* __restrict__ vn, const u16* __restrict__ U,
                                               const u16* __restrict__ cwA, const float* __restrict__ cb,
                                               u16* __restrict__ ug) {
  __shared__ __align__(16) u16 vnT[258 * 72];   // [vrow = f_local + tap][ti], pad 72
  int bx = blockIdx.x;
  int n = bx & 127, b = (bx >> 7) & 3, h = bx >> 9;
  int tid = threadIdx.x;
  int lane = tid & 63, wid = tid >> 6;

  {
    int ti = tid & 63;
    size_t rowbase = ((size_t)((b * 64 + ti) * 128 + n)) * 512;
    #pragma unroll
    for (int it = 0; it < 8; it++) {
      int fq = (tid >> 6) + it * 4;   // 0..31
      uint4 raw = *(const uint4*)(vn + rowbase + h * 256 + fq * 8);
      u16* rp = (u16*)&raw;
      int vr = fq * 8 + 1;
      #pragma unroll
      for (int j = 0; j < 8; j++) vnT[(vr + j) * 72 + ti] = rp[j];
    }
    if (tid < 64) {
      vnT[0 * 72 + ti]   = (h == 0) ? (u16)0 : vn[rowbase + 255];
      vnT[257 * 72 + ti] = (h == 1) ? (u16)0 : vn[rowbase + 256];
    }
  }
  __syncthreads();

  f32x4 zero = {0.f, 0.f, 0.f, 0.f};
  f32x4 acc[4][4];
  #pragma unroll
  for (int m = 0; m < 4; m++)
    #pragma unroll
    for (int nn = 0; nn < 4; nn++) acc[m][nn] = zero;

  #pragma unroll
  for (int s = 0; s < 6; s++) {
    int tap = s >> 1;
    int K0 = s * 32;
    int tig = (s & 1) * 32 + (lane >> 4) * 8;
    short8 af[4], bf[4];
    #pragma unroll
    for (int m = 0; m < 4; m++) {
      int t = m * 16 + (lane & 15);
      af[m] = *(const short8*)(cwA + t * 192 + K0 + (lane >> 4) * 8);
    }
    #pragma unroll
    for (int nn = 0; nn < 4; nn++) {
      int fl = wid * 64 + nn * 16 + (lane & 15);
      int vr = fl + tap;
      bf[nn] = *(const short8*)(vnT + vr * 72 + tig);
    }
    #pragma unroll
    for (int m = 0; m < 4; m++)
      #pragma unroll
      for (int nn = 0; nn < 4; nn++)
        acc[m][nn] = __builtin_amdgcn_mfma_f32_16x16x32_bf16(af[m], bf[nn], acc[m][nn], 0, 0, 0);
  }

  #pragma unroll
  for (int m = 0; m < 4; m++) {
    #pragma unroll
    for (int nn = 0; nn < 4; nn++) {
      int fl = wid * 64 + nn * 16 + (lane & 15);
      int fg = h * 256 + fl;
      #pragma unroll
      for (int r = 0; r < 4; r++) {
        int t = m * 16 + (lane >> 4) * 4 + r;
        size_t row = ((size_t)((b * 64 + t) * 128 + n)) * 512 + fg;
        float g = b2f(U[row]) * (acc[m][nn][r] + cb[t]);
        ug[row] = f2b(g);
      }
    }
  }
}

// ---------- launch ----------
extern "C" void kernel_launch(void* const* d_in, const int* in_sizes, int n_in,
                              void* d_out, int out_size, void* d_ws, size_t ws_size,
                              hipStream_t stream) {
  if (ws_size < WS_NEED) return;
  const float* x = (const float*)d_in[0];
  const int* cir = (const int*)d_in[1];
  auto F32 = [&](int i) { return (const float*)d_in[i]; };

  char* W = (char*)d_ws;
  float* aBin   = (float*)(W + OFF_ABIN);
  float* dinv   = (float*)(W + OFF_DINV);
  float* colsum = (float*)(W + OFF_COLS);
  u16*   ahatT  = (u16*)(W + OFF_AHT);
  u16*   W1c    = (u16*)(W + OFF_W1);
  float* b1c    = (float*)(W + OFF_B1);
  u16*   GWc    = (u16*)(W + OFF_GW);
  float* cvec   = (float*)(W + OFF_CVEC);
  u16*   W2c    = (u16*)(W + OFF_W2);
  u16*   BW     = (u16*)(W + OFF_BW);
  float* btot   = (float*)(W + OFF_BTOT);
  u16*   cwA    = (u16*)(W + OFF_CWT);
  u16*   xhat   = (u16*)(W + OFF_XHAT);
  u16*   Ub     = (u16*)(W + OFF_U);
  u16*   Vb     = (u16*)(W + OFF_V);
  u16*   S3     = (u16*)(W + OFF_S3);
  u16*   Ycat   = (u16*)(W + OFF_Y);

  // prep
  k_adj1<<<128, 128, 0, stream>>>(cir, aBin);
  k_adj2<<<1, 128, 0, stream>>>(aBin, dinv);
  k_adj3<<<128, 128, 0, stream>>>(aBin, dinv, ahatT);
  k_adj4<<<1, 128, 0, stream>>>(aBin, dinv, colsum);
  for (int p = 0; p < 3; p++) {
    int base = 2 + 8 * p;
    k_prep_w1<<<1024, 64, 0, stream>>>(F32(base + 2), F32(base + 0), F32(base + 1), F32(base + 3),
                                       W1c + (size_t)p * 1024 * 256, b1c + p * 1024);
    k_b16cvt<<<256, 64, 0, stream>>>(F32(base + 6), W2c + (size_t)p * 256 * 512);
  }
  k_prep_gw<<<512, 64, 0, stream>>>(F32(28), F32(14), F32(15), GWc, cvec);
  k_prep_gw<<<512, 64, 0, stream>>>(F32(30), F32(22), F32(23), GWc + 512 * 512, cvec + 512);
  k_prep_wout<<<256, 64, 0, stream>>>(F32(38), F32(39), F32(32), F32(33), F32(34), F32(35),
                                      F32(36), F32(37), BW, btot);
  k_prep_cwA<<<64, 192, 0, stream>>>(F32(26), cwA);

  // shared LN(x)
  k_ln1<<<8192, 256, 0, stream>>>(x, xhat);

  // ---- branch t (conv) ----
  k_gemm<256, 0><<<dim3(256, 8), 256, 0, stream>>>(xhat, W1c, b1c, nullptr, Ub, Vb);
  k_lnv<1><<<8192, 256, 0, stream>>>(Vb, S3, F32(6), F32(7));
  k_convm<<<1024, 256, 0, stream>>>(S3, Ub, cwA, F32(27), Vb);
  k_gemm<512, 2><<<dim3(256, 2), 256, 0, stream>>>(Vb, W2c, F32(9), x, (void*)S3, nullptr);
  k_lny<<<8192, 256, 0, stream>>>((const float*)S3, Ycat, 0);

  // ---- branch s (GCN) ----
  k_gemm<256, 0><<<dim3(256, 8), 256, 0, stream>>>(xhat, W1c + (size_t)1 * 1024 * 256, b1c + 1024,
                                                   nullptr, Ub, Vb);
  k_lnv<0><<<8192, 256, 0, stream>>>(Vb, S3, nullptr, nullptr);
  k_gcn<<<dim3(256, 4), 256, 0, stream>>>(S3, GWc, Ub, ahatT, colsum, cvec, F32(29), Vb);
  k_gemm<512, 2><<<dim3(256, 2), 256, 0, stream>>>(Vb, W2c + (size_t)1 * 256 * 512, F32(17), x,
                                                   (void*)S3, nullptr);
  k_lny<<<8192, 256, 0, stream>>>((const float*)S3, Ycat, 256);

  // ---- branch c (GCN) ----
  k_gemm<256, 0><<<dim3(256, 8), 256, 0, stream>>>(xhat, W1c + (size_t)2 * 1024 * 256, b1c + 2048,
                                                   nullptr, Ub, Vb);
  k_lnv<0><<<8192, 256, 0, stream>>>(Vb, S3, nullptr, nullptr);
  k_gcn<<<dim3(256, 4), 256, 0, stream>>>(S3, GWc + 512 * 512, Ub, ahatT, colsum, cvec + 512, F32(31), Vb);
  k_gemm<512, 2><<<dim3(256, 2), 256, 0, stream>>>(Vb, W2c + (size_t)2 * 256 * 512, F32(25), x,
                                                   (void*)S3, nullptr);
  k_lny<<<8192, 256, 0, stream>>>((const float*)S3, Ycat, 512);

  // ---- final projection ----
  k_gemm<768, 2><<<dim3(256, 2), 256, 0, stream>>>(Ycat, BW, btot, x, d_out, nullptr);
}

// Round 10
// 578.340 us; speedup vs baseline: 1.5808x; 1.0288x over previous
//
#include <hip/hip_runtime.h>
#include <hip/hip_bf16.h>

typedef unsigned short u16;
typedef unsigned int u32;
typedef __attribute__((ext_vector_type(4))) float f32x4;
typedef __attribute__((ext_vector_type(8))) short short8;

#define DEV __device__ __forceinline__

// ---------- constants ----------
constexpr int Bc = 4, Tc = 64, Nc = 128, Dc = 256, Fc = 512;
constexpr int R = Bc * Tc * Nc;   // 32768 rows

// ---------- ws layout (bytes) ----------
constexpr size_t OFF_DINV = 0;           // f32 [128]              1024
constexpr size_t OFF_COLS = 1024;        // f32 [128]              1024
constexpr size_t OFF_AHT  = 2048;        // bf16 ahatT [c][r]      32768
constexpr size_t OFF_W1   = 34816;       // bf16 [3][1024][256]    1572864
constexpr size_t OFF_B1   = 1607680;     // f32 [3][1024]          12288
constexpr size_t OFF_GW   = 1619968;     // bf16 [2][512][512]     1048576
constexpr size_t OFF_CVEC = 2668544;     // f32 [2][512]           4096
constexpr size_t OFF_GWS  = 2672640;     // f32 [2][512]           4096
constexpr size_t OFF_W2   = 2676736;     // bf16 [3][256][512]     786432
constexpr size_t OFF_BW   = 3463168;     // bf16 [256][768]        393216
constexpr size_t OFF_BTOT = 3856384;     // f32 [256]              1024
constexpr size_t OFF_CWA  = 3857408;     // bf16 cwA [64][192]     24576
constexpr size_t OFF_VST  = 3881984;     // f32 [R][2]             262144 (ends 4144128)
constexpr size_t OFF_XHAT = 4194304;     // bf16 [R][256]          16777216
constexpr size_t OFF_U    = 20971520;    // bf16 [R][512]          33554432
constexpr size_t OFF_V    = 54525952;    // bf16 [R][512] / f32 [R][256]
constexpr size_t OFF_S3   = 88080384;    // bf16 [R][512] / f32 [R][256]
constexpr size_t OFF_Y    = 121634816;   // bf16 [R][768]          50331648
constexpr size_t WS_NEED  = 171966464;

// ---------- helpers ----------
DEV u16 f2b(float f) { __hip_bfloat16 h = __float2bfloat16(f); return *(u16*)&h; }
DEV float b2f(u16 u) { union { u32 i; float f; } v; v.i = ((u32)u) << 16; return v.f; }
DEV u32 pack2(float a, float b) { return (u32)f2b(a) | ((u32)f2b(b) << 16); }
DEV float wave_sum(float s) {
  #pragma unroll
  for (int o = 32; o; o >>= 1) s += __shfl_xor(s, o);
  return s;
}
// tanh-approx gelu (branch-free, NaN-safe; |err| vs erf-gelu <= ~2e-3)
DEV float gelu(float v) {
  float t = v * v;
  float e = __expf(v * (1.5957691f + 0.0713548162f * t));
  return v - v * __builtin_amdgcn_rcpf(e + 1.0f);
}
DEV void gload16(const u16* g, u16* l) {
  __builtin_amdgcn_global_load_lds((const __attribute__((address_space(1))) void*)g,
                                   (__attribute__((address_space(3))) void*)l, 16, 0, 0);
}
DEV void wait_lgkm0() { asm volatile("s_waitcnt lgkmcnt(0)" ::: "memory"); __builtin_amdgcn_sched_barrier(0); }
DEV void wait_vm0()   { asm volatile("s_waitcnt vmcnt(0)" ::: "memory");  __builtin_amdgcn_sched_barrier(0); }
DEV void wait_vm8()   { asm volatile("s_waitcnt vmcnt(8)" ::: "memory");  __builtin_amdgcn_sched_barrier(0); }

// ---------- adjacency (aBin recomputed from cir each time) ----------
DEV float adj(const int* cir, int r, int c) {
  return (cir[r * 128 + c] != 0 || r == c) ? 1.f : 0.f;
}
__global__ void k_adj2(const int* __restrict__ cir, float* __restrict__ dinv) {
  int c = threadIdx.x; float s = 0.f;
  for (int r = 0; r < 128; r++) s += adj(cir, r, c);
  dinv[c] = rsqrtf(s);
}
// ahatT[c][r] = a_hat[r][c]
__global__ void k_adj3(const int* __restrict__ cir, const float* __restrict__ dinv,
                       u16* __restrict__ ahatT) {
  int c = blockIdx.x, r = threadIdx.x;
  ahatT[c * 128 + r] = f2b(adj(cir, r, c) * dinv[r] * dinv[c]);
}
__global__ void k_adj4(const int* __restrict__ cir, const float* __restrict__ dinv,
                       float* __restrict__ colsum) {
  int c = threadIdx.x; float s = 0.f;
  for (int r = 0; r < 128; r++) s += adj(cir, r, c) * dinv[r];
  colsum[c] = s * dinv[c];
}

// ---------- weight prep ----------
__global__ void k_prep_w1(const float* __restrict__ w1, const float* __restrict__ ng,
                          const float* __restrict__ nb, const float* __restrict__ b1,
                          u16* __restrict__ w1o, float* __restrict__ b1o) {
  int k = blockIdx.x, lane = threadIdx.x;
  float4 wv = *(const float4*)(w1 + k * 256 + lane * 4);
  float4 gv = *(const float4*)(ng + lane * 4);
  float4 bv = *(const float4*)(nb + lane * 4);
  uint2 o; o.x = pack2(wv.x * gv.x, wv.y * gv.y); o.y = pack2(wv.z * gv.z, wv.w * gv.w);
  *(uint2*)(w1o + k * 256 + lane * 4) = o;
  float acc = wv.x * bv.x + wv.y * bv.y + wv.z * bv.z + wv.w * bv.w;
  acc = wave_sum(acc);
  if (lane == 0) b1o[k] = b1[k] + acc;
}
// gwo = gw*sg (bf16); cvo[f] = sum_e gw*sb; gwso[f] = sum_e gw*sg
__global__ void k_prep_gw(const float* __restrict__ gw, const float* __restrict__ sg,
                          const float* __restrict__ sb, u16* __restrict__ gwo,
                          float* __restrict__ cvo, float* __restrict__ gwso) {
  int f = blockIdx.x, lane = threadIdx.x;
  uint4 o;
  float4 w0 = *(const float4*)(gw + f * 512 + lane * 8);
  float4 w1 = *(const float4*)(gw + f * 512 + lane * 8 + 4);
  float4 g0 = *(const float4*)(sg + lane * 8);
  float4 g1 = *(const float4*)(sg + lane * 8 + 4);
  float4 b0 = *(const float4*)(sb + lane * 8);
  float4 b1 = *(const float4*)(sb + lane * 8 + 4);
  float p0 = w0.x * g0.x, p1 = w0.y * g0.y, p2 = w0.z * g0.z, p3 = w0.w * g0.w;
  float p4 = w1.x * g1.x, p5 = w1.y * g1.y, p6 = w1.z * g1.z, p7 = w1.w * g1.w;
  o.x = pack2(p0, p1); o.y = pack2(p2, p3); o.z = pack2(p4, p5); o.w = pack2(p6, p7);
  *(uint4*)(gwo + f * 512 + lane * 8) = o;
  float accb = w0.x * b0.x + w0.y * b0.y + w0.z * b0.z + w0.w * b0.w
             + w1.x * b1.x + w1.y * b1.y + w1.z * b1.z + w1.w * b1.w;
  float accg = p0 + p1 + p2 + p3 + p4 + p5 + p6 + p7;
  accb = wave_sum(accb);
  accg = wave_sum(accg);
  if (lane == 0) { cvo[f] = accb; gwso[f] = accg; }
}
__global__ void k_b16cvt(const float* __restrict__ src, u16* __restrict__ dst) {
  int idx = (blockIdx.x * 64 + threadIdx.x) * 8;
  float4 a = *(const float4*)(src + idx);
  float4 b = *(const float4*)(src + idx + 4);
  uint4 o; o.x = pack2(a.x, a.y); o.y = pack2(a.z, a.w);
  o.z = pack2(b.x, b.y); o.w = pack2(b.z, b.w);
  *(uint4*)(dst + idx) = o;
}
__global__ void k_prep_wout(const float* __restrict__ wout, const float* __restrict__ bout,
                            const float* __restrict__ g1, const float* __restrict__ b1,
                            const float* __restrict__ g2, const float* __restrict__ b2,
                            const float* __restrict__ g3, const float* __restrict__ b3,
                            u16* __restrict__ bw, float* __restrict__ bt) {
  int o = blockIdx.x, lane = threadIdx.x;
  float acc = 0.f;
  #pragma unroll
  for (int j = 0; j < 12; j++) {
    int c = lane + j * 64;
    int p = c >> 8, i = c & 255;
    const float* gg = (p == 0) ? g1 : (p == 1) ? g2 : g3;
    const float* bb = (p == 0) ? b1 : (p == 1) ? b2 : b3;
    float w = wout[o * 768 + c];
    bw[o * 768 + c] = f2b(w * gg[i]);
    acc += w * bb[i];
  }
  acc = wave_sum(acc);
  if (lane == 0) bt[o] = bout[o] + acc;
}
// cwA[t][K] with K = tap*64 + ti, from cw[t][ti][0][tap]
__global__ void k_prep_cwA(const float* __restrict__ cw, u16* __restrict__ cwA) {
  int t = blockIdx.x, q = threadIdx.x;   // q = 0..191
  int tap = q >> 6, ti = q & 63;
  cwA[t * 192 + q] = f2b(cw[t * 192 + ti * 3 + tap]);
}

// ---------- LN kernels ----------
__global__ __launch_bounds__(256) void k_ln1(const float* __restrict__ x, u16* __restrict__ xhat) {
  int row = blockIdx.x * 4 + (threadIdx.x >> 6);
  int lane = threadIdx.x & 63;
  float4 v = *(const float4*)(x + (size_t)row * 256 + lane * 4);
  float s = v.x + v.y + v.z + v.w;
  float s2 = v.x * v.x + v.y * v.y + v.z * v.z + v.w * v.w;
  s = wave_sum(s); s2 = wave_sum(s2);
  float m = s * (1.f / 256.f);
  float var = s2 * (1.f / 256.f) - m * m;
  float rs = rsqrtf(var + 1e-5f);
  uint2 o; o.x = pack2((v.x - m) * rs, (v.y - m) * rs); o.y = pack2((v.z - m) * rs, (v.w - m) * rs);
  *(uint2*)(xhat + (size_t)row * 256 + lane * 4) = o;
}

// conv branch: LN over 512 then *sg+sb
__global__ __launch_bounds__(256) void k_lnv(const u16* __restrict__ Vin, u16* __restrict__ Vout,
                                             const float* __restrict__ sg, const float* __restrict__ sb) {
  int row = blockIdx.x * 4 + (threadIdx.x >> 6);
  int lane = threadIdx.x & 63;
  uint4 raw = *(const uint4*)(Vin + (size_t)row * 512 + lane * 8);
  u16* rp = (u16*)&raw;
  float f[8], s = 0.f, s2 = 0.f;
  #pragma unroll
  for (int j = 0; j < 8; j++) { f[j] = b2f(rp[j]); s += f[j]; s2 += f[j] * f[j]; }
  s = wave_sum(s); s2 = wave_sum(s2);
  float m = s * (1.f / 512.f);
  float var = s2 * (1.f / 512.f) - m * m;
  float rs = rsqrtf(var + 1e-5f);
  float4 g0 = *(const float4*)(sg + lane * 8);
  float4 g1 = *(const float4*)(sg + lane * 8 + 4);
  float4 b0 = *(const float4*)(sb + lane * 8);
  float4 b1 = *(const float4*)(sb + lane * 8 + 4);
  float o[8];
  o[0] = (f[0] - m) * rs * g0.x + b0.x; o[1] = (f[1] - m) * rs * g0.y + b0.y;
  o[2] = (f[2] - m) * rs * g0.z + b0.z; o[3] = (f[3] - m) * rs * g0.w + b0.w;
  o[4] = (f[4] - m) * rs * g1.x + b1.x; o[5] = (f[5] - m) * rs * g1.y + b1.y;
  o[6] = (f[6] - m) * rs * g1.z + b1.z; o[7] = (f[7] - m) * rs * g1.w + b1.w;
  uint4 ov; ov.x = pack2(o[0], o[1]); ov.y = pack2(o[2], o[3]);
  ov.z = pack2(o[4], o[5]); ov.w = pack2(o[6], o[7]);
  *(uint4*)(Vout + (size_t)row * 512 + lane * 8) = ov;
}

__global__ __launch_bounds__(256) void k_lny(const float* __restrict__ Y, u16* __restrict__ Ycat, int colofs) {
  int row = blockIdx.x * 4 + (threadIdx.x >> 6);
  int lane = threadIdx.x & 63;
  float4 v = *(const float4*)(Y + (size_t)row * 256 + lane * 4);
  float s = v.x + v.y + v.z + v.w;
  float s2 = v.x * v.x + v.y * v.y + v.z * v.z + v.w * v.w;
  s = wave_sum(s); s2 = wave_sum(s2);
  float m = s * (1.f / 256.f);
  float var = s2 * (1.f / 256.f) - m * m;
  float rs = rsqrtf(var + 1e-5f);
  uint2 o; o.x = pack2((v.x - m) * rs, (v.y - m) * rs); o.y = pack2((v.z - m) * rs, (v.w - m) * rs);
  *(uint2*)(Ycat + (size_t)row * 768 + colofs + lane * 4) = o;
}

// ---------- staging: direct global->LDS with source-side swizzle ----------
template <int KDIM>
DEV void stage_tile(const u16* __restrict__ G, u16* lds, int row0, int tid) {
  #pragma unroll
  for (int i = 0; i < 4; i++) {
    int qq = tid + i * 256;
    int row = qq >> 3, kc = qq & 7;
    int kg = kc ^ (row & 7);
    gload16(G + (size_t)(row0 + row) * KDIM + kg * 8, lds + qq * 8);
  }
}

// one 64-wide K-step of MFMA on a staged tile pair
DEV void mfma_step(const u16* As, const u16* Bs, f32x4 (&acc)[4][4], int lane, int wr, int wc) {
  #pragma unroll
  for (int kk = 0; kk < 2; kk++) {
    int kb = kk * 64 + (lane >> 4) * 16;
    short8 af[4], bfr[4];
    #pragma unroll
    for (int m = 0; m < 4; m++) {
      int row = wr * 64 + m * 16 + (lane & 15);
      af[m] = *(const short8*)((const char*)As + ((row * 128 + kb) ^ ((row & 7) << 4)));
    }
    #pragma unroll
    for (int n = 0; n < 4; n++) {
      int col = wc * 64 + n * 16 + (lane & 15);
      bfr[n] = *(const short8*)((const char*)Bs + ((col * 128 + kb) ^ ((col & 7) << 4)));
    }
    #pragma unroll
    for (int m = 0; m < 4; m++)
      #pragma unroll
      for (int n = 0; n < 4; n++)
        acc[m][n] = __builtin_amdgcn_mfma_f32_16x16x32_bf16(af[m], bfr[n], acc[m][n], 0, 0, 0);
  }
}

// counted-vmcnt K-loop body (T4: never drain to 0 mid-loop). Buffers: pair i at
// lds + i*16384 u16 (A) / +8192 (B). Prologue must have staged tiles 0,1.
template <int KDIM, int NT>
DEV void pipe_kloop(const u16* __restrict__ A, const u16* __restrict__ Bt, u16* lds,
                    f32x4 (&acc)[4][4], int rowA0, int colB0, int tid, int lane, int wr, int wc) {
  #pragma unroll
  for (int it = 0; it < NT; ++it) {
    if (it + 1 < NT) wait_vm8();   // tile it complete; tile it+1's 8 loads may stay in flight
    else             wait_vm0();
    __builtin_amdgcn_s_barrier();
    const u16* Asc = lds + (it & 1) * 16384;
    mfma_step(Asc, Asc + 8192, acc, lane, wr, wc);
    wait_lgkm0();
    __builtin_amdgcn_s_barrier();
    if (it + 2 < NT) {
      stage_tile<KDIM>(A + (it + 2) * 64, lds + (it & 1) * 16384, rowA0, tid);
      stage_tile<KDIM>(Bt + (it + 2) * 64, lds + (it & 1) * 16384 + 8192, colB0, tid);
    }
  }
}

// ---------- MFMA GEMM ----------
// EPI 0: gelu(acc+bias) split-store bf16 (u->out0, v->out1); if vstat&&v-block, accumulate
//        per-row sum/sumsq of v via 16-lane reduce + atomicAdd (for downstream LN fold).
// EPI 2: acc + bias[col] + xres -> f32 out0 (stride 256)
template <int KDIM, int EPI>
__global__ __launch_bounds__(256) void k_gemm(const u16* __restrict__ A, const u16* __restrict__ Bt,
                                              const float* __restrict__ bias,
                                              const float* __restrict__ xres,
                                              void* __restrict__ out0, void* __restrict__ out1,
                                              float* __restrict__ vstat) {
  __shared__ __align__(16) u16 lds[4 * 16384 / 2];   // 2 tile-pairs, 64KB
  const int tid = threadIdx.x;
  const int lane = tid & 63, wid = tid >> 6;
  const int wr = wid >> 1, wc = wid & 1;
  const int rowA0 = blockIdx.x * 128;
  const int colB0 = blockIdx.y * 128;
  constexpr int NT = KDIM / 64;

  f32x4 zero = {0.f, 0.f, 0.f, 0.f};
  f32x4 acc[4][4];
  #pragma unroll
  for (int m = 0; m < 4; m++)
    #pragma unroll
    for (int n = 0; n < 4; n++) acc[m][n] = zero;

  stage_tile<KDIM>(A, lds, rowA0, tid);
  stage_tile<KDIM>(Bt, lds + 8192, colB0, tid);
  stage_tile<KDIM>(A + 64, lds + 16384, rowA0, tid);
  stage_tile<KDIM>(Bt + 64, lds + 24576, colB0, tid);
  pipe_kloop<KDIM, NT>(A, Bt, lds, acc, rowA0, colB0, tid, lane, wr, wc);

  if (EPI == 0) {
    float s1a[4][4], s2a[4][4];
    #pragma unroll
    for (int m = 0; m < 4; m++)
      #pragma unroll
      for (int r = 0; r < 4; r++) { s1a[m][r] = 0.f; s2a[m][r] = 0.f; }
    #pragma unroll
    for (int m = 0; m < 4; m++) {
      #pragma unroll
      for (int n = 0; n < 4; n++) {
        int col = colB0 + wc * 64 + n * 16 + (lane & 15);
        float bcol = bias[col];
        #pragma unroll
        for (int r = 0; r < 4; r++) {
          int row = rowA0 + wr * 64 + m * 16 + (lane >> 4) * 4 + r;
          float v = gelu(acc[m][n][r] + bcol);
          s1a[m][r] += v; s2a[m][r] += v * v;
          u16 hv = f2b(v);
          if (col < 512) ((u16*)out0)[(size_t)row * 512 + col] = hv;
          else           ((u16*)out1)[(size_t)row * 512 + col - 512] = hv;
        }
      }
    }
    if (vstat != nullptr && colB0 >= 512) {
      #pragma unroll
      for (int m = 0; m < 4; m++) {
        #pragma unroll
        for (int r = 0; r < 4; r++) {
          float s1 = s1a[m][r], s2 = s2a[m][r];
          s1 += __shfl_xor(s1, 1); s2 += __shfl_xor(s2, 1);
          s1 += __shfl_xor(s1, 2); s2 += __shfl_xor(s2, 2);
          s1 += __shfl_xor(s1, 4); s2 += __shfl_xor(s2, 4);
          s1 += __shfl_xor(s1, 8); s2 += __shfl_xor(s2, 8);
          if ((lane & 15) == 0) {
            int row = rowA0 + wr * 64 + m * 16 + (lane >> 4) * 4 + r;
            atomicAdd(vstat + 2 * row, s1);
            atomicAdd(vstat + 2 * row + 1, s2);
          }
        }
      }
    }
  } else {
    #pragma unroll
    for (int m = 0; m < 4; m++) {
      #pragma unroll
      for (int n = 0; n < 4; n++) {
        int col = colB0 + wc * 64 + n * 16 + (lane & 15);
        #pragma unroll
        for (int r = 0; r < 4; r++) {
          int row = rowA0 + wr * 64 + m * 16 + (lane >> 4) * 4 + r;
          float v = acc[m][n][r] + bias[col] + xres[(size_t)row * 256 + col];
          ((float*)out0)[(size_t)row * 256 + col] = v;
        }
      }
    }
  }
}

// ---------- fused GCN on RAW v with LN folded algebraically ----------
// raw = v@GWc^T (K=512); glin = rs_n*raw - (rs_n*m_n)*S[f]  (S[f]=sum_e GWc[f,e]);
// agg = ahatT@glin; ug = U*(agg + colsum[c]*cvec[f] + gb[f])
__global__ __launch_bounds__(256) void k_gcn(const u16* __restrict__ A, const u16* __restrict__ Bt,
                                             const u16* __restrict__ U, const u16* __restrict__ ahatT,
                                             const float* __restrict__ colsum, const float* __restrict__ cvec,
                                             const float* __restrict__ gwsum, const float* __restrict__ gb,
                                             const float* __restrict__ vstat, u16* __restrict__ ug) {
  __shared__ __align__(16) char smem[65536];   // 2 tile-pairs (64KB); reused as glinT 128x136 u16
  u16* lds = (u16*)smem;
  u16* glinT = (u16*)smem;
  const int tid = threadIdx.x;
  const int lane = tid & 63, wid = tid >> 6;
  const int wr = wid >> 1, wc = wid & 1;
  const int rowA0 = blockIdx.x * 128;
  const int colB0 = blockIdx.y * 128;

  f32x4 zero = {0.f, 0.f, 0.f, 0.f};
  f32x4 acc[4][4];
  #pragma unroll
  for (int m = 0; m < 4; m++)
    #pragma unroll
    for (int n = 0; n < 4; n++) acc[m][n] = zero;

  stage_tile<512>(A, lds, rowA0, tid);
  stage_tile<512>(Bt, lds + 8192, colB0, tid);
  stage_tile<512>(A + 64, lds + 16384, rowA0, tid);
  stage_tile<512>(Bt + 64, lds + 24576, colB0, tid);
  pipe_kloop<512, 8>(A, Bt, lds, acc, rowA0, colB0, tid, lane, wr, wc);

  // per-row LN coefficients from vstat
  float rsv[4][4], rsmv[4][4];
  #pragma unroll
  for (int m = 0; m < 4; m++)
    #pragma unroll
    for (int r = 0; r < 4; r++) {
      int row = rowA0 + wr * 64 + m * 16 + (lane >> 4) * 4 + r;
      float st0 = vstat[2 * row], st1 = vstat[2 * row + 1];
      float mean = st0 * (1.f / 512.f);
      float var = fmaxf(st1 * (1.f / 512.f) - mean * mean, 0.f);
      float rs = rsqrtf(var + 1e-5f);
      rsv[m][r] = rs; rsmv[m][r] = rs * mean;
    }

  // write glinT[f][n] with affine fold
  #pragma unroll
  for (int m = 0; m < 4; m++) {
    #pragma unroll
    for (int n = 0; n < 4; n++) {
      int fl = wc * 64 + n * 16 + (lane & 15);
      float S = gwsum[colB0 + fl];
      int n0 = wr * 64 + m * 16 + (lane >> 4) * 4;
      float v0 = rsv[m][0] * acc[m][n][0] - rsmv[m][0] * S;
      float v1 = rsv[m][1] * acc[m][n][1] - rsmv[m][1] * S;
      float v2 = rsv[m][2] * acc[m][n][2] - rsmv[m][2] * S;
      float v3 = rsv[m][3] * acc[m][n][3] - rsmv[m][3] * S;
      u32* p = (u32*)(glinT + fl * 136 + n0);
      p[0] = pack2(v0, v1);
      p[1] = pack2(v2, v3);
    }
  }
  __syncthreads();

  // stage 2: C2[c][f] = sum_r ahatT[c][r] * glin[r][f]
  f32x4 acc2[4][4];
  #pragma unroll
  for (int m = 0; m < 4; m++)
    #pragma unroll
    for (int n = 0; n < 4; n++) acc2[m][n] = zero;
  #pragma unroll
  for (int ks = 0; ks < 4; ks++) {
    short8 a2[4], b2v[4];
    #pragma unroll
    for (int m = 0; m < 4; m++) {
      int c = wr * 64 + m * 16 + (lane & 15);
      a2[m] = *(const short8*)(ahatT + c * 128 + ks * 32 + (lane >> 4) * 8);
    }
    #pragma unroll
    for (int n = 0; n < 4; n++) {
      int f = wc * 64 + n * 16 + (lane & 15);
      b2v[n] = *(const short8*)(glinT + f * 136 + ks * 32 + (lane >> 4) * 8);
    }
    #pragma unroll
    for (int m = 0; m < 4; m++)
      #pragma unroll
      for (int n = 0; n < 4; n++)
        acc2[m][n] = __builtin_amdgcn_mfma_f32_16x16x32_bf16(a2[m], b2v[n], acc2[m][n], 0, 0, 0);
  }

  // epilogue: ug = U * (acc2 + colsum[c]*cvec[f] + gb[f])
  #pragma unroll
  for (int m = 0; m < 4; m++) {
    #pragma unroll
    for (int n = 0; n < 4; n++) {
      int fl = wc * 64 + n * 16 + (lane & 15);
      int fg = colB0 + fl;
      float cv = cvec[fg], gbv = gb[fg];
      #pragma unroll
      for (int r = 0; r < 4; r++) {
        int c = wr * 64 + m * 16 + (lane >> 4) * 4 + r;
        size_t row = (size_t)(rowA0 + c) * 512 + fg;
        float g = b2f(U[row]) * (acc2[m][n][r] + colsum[c] * cv + gbv);
        ug[row] = f2b(g);
      }
    }
  }
}

// ---------- MFMA conv over T ----------
__global__ __launch_bounds__(256) void k_convm(const u16* __restrict__ vn, const u16* __restrict__ U,
                                               const u16* __restrict__ cwA, const float* __restrict__ cb,
                                               u16* __restrict__ ug) {
  __shared__ __align__(16) u16 vnT[258 * 72];   // [vrow = f_local + tap][ti], pad 72
  int bx = blockIdx.x;
  int n = bx & 127, b = (bx >> 7) & 3, h = bx >> 9;
  int tid = threadIdx.x;
  int lane = tid & 63, wid = tid >> 6;

  {
    int ti = tid & 63;
    size_t rowbase = ((size_t)((b * 64 + ti) * 128 + n)) * 512;
    #pragma unroll
    for (int it = 0; it < 8; it++) {
      int fq = (tid >> 6) + it * 4;   // 0..31
      uint4 raw = *(const uint4*)(vn + rowbase + h * 256 + fq * 8);
      u16* rp = (u16*)&raw;
      int vr = fq * 8 + 1;
      #pragma unroll
      for (int j = 0; j < 8; j++) vnT[(vr + j) * 72 + ti] = rp[j];
    }
    if (tid < 64) {
      vnT[0 * 72 + ti]   = (h == 0) ? (u16)0 : vn[rowbase + 255];
      vnT[257 * 72 + ti] = (h == 1) ? (u16)0 : vn[rowbase + 256];
    }
  }
  __syncthreads();

  f32x4 zero = {0.f, 0.f, 0.f, 0.f};
  f32x4 acc[4][4];
  #pragma unroll
  for (int m = 0; m < 4; m++)
    #pragma unroll
    for (int nn = 0; nn < 4; nn++) acc[m][nn] = zero;

  #pragma unroll
  for (int s = 0; s < 6; s++) {
    int tap = s >> 1;
    int K0 = s * 32;
    int tig = (s & 1) * 32 + (lane >> 4) * 8;
    short8 af[4], bf[4];
    #pragma unroll
    for (int m = 0; m < 4; m++) {
      int t = m * 16 + (lane & 15);
      af[m] = *(const short8*)(cwA + t * 192 + K0 + (lane >> 4) * 8);
    }
    #pragma unroll
    for (int nn = 0; nn < 4; nn++) {
      int fl = wid * 64 + nn * 16 + (lane & 15);
      int vr = fl + tap;
      bf[nn] = *(const short8*)(vnT + vr * 72 + tig);
    }
    #pragma unroll
    for (int m = 0; m < 4; m++)
      #pragma unroll
      for (int nn = 0; nn < 4; nn++)
        acc[m][nn] = __builtin_amdgcn_mfma_f32_16x16x32_bf16(af[m], bf[nn], acc[m][nn], 0, 0, 0);
  }

  #pragma unroll
  for (int m = 0; m < 4; m++) {
    #pragma unroll
    for (int nn = 0; nn < 4; nn++) {
      int fl = wid * 64 + nn * 16 + (lane & 15);
      int fg = h * 256 + fl;
      #pragma unroll
      for (int r = 0; r < 4; r++) {
        int t = m * 16 + (lane >> 4) * 4 + r;
        size_t row = ((size_t)((b * 64 + t) * 128 + n)) * 512 + fg;
        float g = b2f(U[row]) * (acc[m][nn][r] + cb[t]);
        ug[row] = f2b(g);
      }
    }
  }
}

// ---------- launch ----------
extern "C" void kernel_launch(void* const* d_in, const int* in_sizes, int n_in,
                              void* d_out, int out_size, void* d_ws, size_t ws_size,
                              hipStream_t stream) {
  if (ws_size < WS_NEED) return;
  const float* x = (const float*)d_in[0];
  const int* cir = (const int*)d_in[1];
  auto F32 = [&](int i) { return (const float*)d_in[i]; };

  char* W = (char*)d_ws;
  float* dinv   = (float*)(W + OFF_DINV);
  float* colsum = (float*)(W + OFF_COLS);
  u16*   ahatT  = (u16*)(W + OFF_AHT);
  u16*   W1c    = (u16*)(W + OFF_W1);
  float* b1c    = (float*)(W + OFF_B1);
  u16*   GWc    = (u16*)(W + OFF_GW);
  float* cvec   = (float*)(W + OFF_CVEC);
  float* gws    = (float*)(W + OFF_GWS);
  u16*   W2c    = (u16*)(W + OFF_W2);
  u16*   BW     = (u16*)(W + OFF_BW);
  float* btot   = (float*)(W + OFF_BTOT);
  u16*   cwA    = (u16*)(W + OFF_CWA);
  float* vstat  = (float*)(W + OFF_VST);
  u16*   xhat   = (u16*)(W + OFF_XHAT);
  u16*   Ub     = (u16*)(W + OFF_U);
  u16*   Vb     = (u16*)(W + OFF_V);
  u16*   S3     = (u16*)(W + OFF_S3);
  u16*   Ycat   = (u16*)(W + OFF_Y);

  // prep
  k_adj2<<<1, 128, 0, stream>>>(cir, dinv);
  k_adj3<<<128, 128, 0, stream>>>(cir, dinv, ahatT);
  k_adj4<<<1, 128, 0, stream>>>(cir, dinv, colsum);
  for (int p = 0; p < 3; p++) {
    int base = 2 + 8 * p;
    k_prep_w1<<<1024, 64, 0, stream>>>(F32(base + 2), F32(base + 0), F32(base + 1), F32(base + 3),
                                       W1c + (size_t)p * 1024 * 256, b1c + p * 1024);
    k_b16cvt<<<256, 64, 0, stream>>>(F32(base + 6), W2c + (size_t)p * 256 * 512);
  }
  k_prep_gw<<<512, 64, 0, stream>>>(F32(28), F32(14), F32(15), GWc, cvec, gws);
  k_prep_gw<<<512, 64, 0, stream>>>(F32(30), F32(22), F32(23), GWc + 512 * 512, cvec + 512, gws + 512);
  k_prep_wout<<<256, 64, 0, stream>>>(F32(38), F32(39), F32(32), F32(33), F32(34), F32(35),
                                      F32(36), F32(37), BW, btot);
  k_prep_cwA<<<64, 192, 0, stream>>>(F32(26), cwA);

  // shared LN(x)
  k_ln1<<<8192, 256, 0, stream>>>(x, xhat);

  // ---- branch t (conv) ----
  k_gemm<256, 0><<<dim3(256, 8), 256, 0, stream>>>(xhat, W1c, b1c, nullptr, Ub, Vb, nullptr);
  k_lnv<<<8192, 256, 0, stream>>>(Vb, S3, F32(6), F32(7));
  k_convm<<<1024, 256, 0, stream>>>(S3, Ub, cwA, F32(27), Vb);
  k_gemm<512, 2><<<dim3(256, 2), 256, 0, stream>>>(Vb, W2c, F32(9), x, (void*)S3, nullptr, nullptr);
  k_lny<<<8192, 256, 0, stream>>>((const float*)S3, Ycat, 0);

  // ---- branch s (GCN) ----
  hipMemsetAsync(vstat, 0, 262144, stream);
  k_gemm<256, 0><<<dim3(256, 8), 256, 0, stream>>>(xhat, W1c + (size_t)1 * 1024 * 256, b1c + 1024,
                                                   nullptr, Ub, Vb, vstat);
  k_gcn<<<dim3(256, 4), 256, 0, stream>>>(Vb, GWc, Ub, ahatT, colsum, cvec, gws, F32(29), vstat, S3);
  k_gemm<512, 2><<<dim3(256, 2), 256, 0, stream>>>(S3, W2c + (size_t)1 * 256 * 512, F32(17), x,
                                                   (void*)Vb, nullptr, nullptr);
  k_lny<<<8192, 256, 0, stream>>>((const float*)Vb, Ycat, 256);

  // ---- branch c (GCN) ----
  hipMemsetAsync(vstat, 0, 262144, stream);
  k_gemm<256, 0><<<dim3(256, 8), 256, 0, stream>>>(xhat, W1c + (size_t)2 * 1024 * 256, b1c + 2048,
                                                   nullptr, Ub, Vb, vstat);
  k_gcn<<<dim3(256, 4), 256, 0, stream>>>(Vb, GWc + 512 * 512, Ub, ahatT, colsum, cvec + 512,
                                          gws + 512, F32(31), vstat, S3);
  k_gemm<512, 2><<<dim3(256, 2), 256, 0, stream>>>(S3, W2c + (size_t)2 * 256 * 512, F32(25), x,
                                                   (void*)Vb, nullptr, nullptr);
  k_lny<<<8192, 256, 0, stream>>>((const float*)Vb, Ycat, 512);

  // ---- final projection ----
  k_gemm<768, 2><<<dim3(256, 2), 256, 0, stream>>>(Ycat, BW, btot, x, d_out, nullptr, nullptr);
}